// Round 1
// baseline (2443.614 us; speedup 1.0000x reference)
//
#include <hip/hip_runtime.h>
#include <math.h>

// Problem constants
#define Bn 2
#define Cc 64
#define Hh 384
#define Ww 384
#define HW (Hh*Ww)          // 147456
#define Tt (Bn*HW)          // 294912 tokens
#define STR 68              // LDS row stride for 64-wide tiles (float4-aligned, 2-way-free banks)
#define QSTR 193            // LDS row stride for 192-wide qkv tile (odd -> conflict-free scalar access)

// ---------------- shared helpers ----------------

__device__ __forceinline__ void stage_w4(float* sWb, const float* __restrict__ gw,
                                         int row_stride_g, int tid) {
  // stage a 64x64 weight tile (row-major, row stride row_stride_g) into LDS [64][STR]
#pragma unroll
  for (int it = 0; it < 4; ++it) {
    int o = it * 16 + (tid >> 4);
    int c = (tid & 15) * 4;
    *(float4*)(sWb + o * STR + c) = *(const float4*)(gw + (long)o * row_stride_g + c);
  }
}

__device__ __forceinline__ void load_tile(float* sAb, const float* __restrict__ g, int tid) {
  // load 64 contiguous tokens x 64 ch into LDS [64][STR]
#pragma unroll
  for (int it = 0; it < 4; ++it) {
    int s = it * 16 + (tid >> 4);
    int c = (tid & 15) * 4;
    *(float4*)(sAb + s * STR + c) = *(const float4*)(g + s * 64 + c);
  }
}

__device__ __forceinline__ void gemm64(const float* sAb, const float* sWb,
                                       float acc[4][4], int t0, int o0) {
  // acc[i][j] += sum_c A[t0+i][c] * W[o0+j][c]
#pragma unroll
  for (int c4 = 0; c4 < 16; ++c4) {
    float4 a[4], w[4];
#pragma unroll
    for (int i = 0; i < 4; ++i) a[i] = *(const float4*)(sAb + (t0 + i) * STR + c4 * 4);
#pragma unroll
    for (int j = 0; j < 4; ++j) w[j] = *(const float4*)(sWb + (o0 + j) * STR + c4 * 4);
#pragma unroll
    for (int i = 0; i < 4; ++i)
#pragma unroll
      for (int j = 0; j < 4; ++j)
        acc[i][j] += a[i].x * w[j].x + a[i].y * w[j].y + a[i].z * w[j].z + a[i].w * w[j].w;
  }
}

__device__ __forceinline__ float gelu_exact(float v) {
  return 0.5f * v * (1.0f + erff(v * 0.70710678118654752f));
}

// ---------------- K1: channel LayerNorm + transpose to token-major ----------------

__global__ __launch_bounds__(256) void k1_ln(const float* __restrict__ x, float* __restrict__ xn,
                                             const float* __restrict__ g1, const float* __restrict__ b1) {
  __shared__ float tile[64 * 65];
  __shared__ float mu[64], rs[64];
  const int tid = threadIdx.x;
  const long p0 = (long)blockIdx.x * 64;
  const int b = (int)(p0 / HW);
  const int rem = (int)(p0 - (long)b * HW);
  const int h = rem / Ww, w0 = rem - (rem / Ww) * Ww;
#pragma unroll
  for (int it = 0; it < 16; ++it) {
    int c = it * 4 + (tid >> 6);
    int wo = tid & 63;
    tile[wo * 65 + c] = x[(((long)(b * Cc + c)) * Hh + h) * Ww + w0 + wo];
  }
  __syncthreads();
  if (tid < 64) {
    float s = 0.f, sq = 0.f;
#pragma unroll
    for (int c = 0; c < 64; ++c) { float v = tile[tid * 65 + c]; s += v; sq += v * v; }
    float m = s * (1.0f / 64.0f);
    float var = sq * (1.0f / 64.0f) - m * m;
    mu[tid] = m; rs[tid] = rsqrtf(var + 1e-5f);
  }
  __syncthreads();
  {
    int c = tid & 63;
    float gw = g1[c], gb = b1[c];
#pragma unroll
    for (int it = 0; it < 16; ++it) {
      int p = (tid >> 6) * 16 + it;
      xn[(p0 + p) * 64 + c] = (tile[p * 65 + c] - mu[p]) * rs[p] * gw + gb;
    }
  }
}

// ---------------- K2: fused per-window REMSA (reads xn, writes remsa-out in place) ----------------

__global__ __launch_bounds__(256) void k2_remsa(
    float* xr,  // in: xn (token-major), out: remsa result (same buffer, own tokens only)
    const float* __restrict__ qkvw, const float* __restrict__ qkvb,
    const float* __restrict__ posb,
    const float* __restrict__ outw, const float* __restrict__ outb,
    const float* __restrict__ cpw, const float* __restrict__ cpb,
    const float* __restrict__ pw1w, const float* __restrict__ pw1b,
    const float* __restrict__ dw1w, const float* __restrict__ dw1b,
    const float* __restrict__ tokw, const float* __restrict__ tokb) {
  __shared__ float sA[64 * STR];   // xw tile (LN'd window input)
  __shared__ float sW[64 * STR];   // streamed weight tile
  __shared__ float sB[64 * STR];   // scratch (convp-out / dw-out / ao)
  __shared__ float sQ[64 * QSTR];  // qkv (192 cols); cols 0..63 reused for pw1-out earlier
  const int tid = threadIdx.x;
  const int blk = blockIdx.x;
  const int b = blk / 2304;
  const int rr = blk - b * 2304;
  const int wy = rr / 48, wx = rr - (rr / 48) * 48;
  const int h0 = wy * 8, w0c = wx * 8;
  const long ibase = (long)b * HW;

  // load window tile: token s=(iy*8+ix) -> raster t
#pragma unroll
  for (int it = 0; it < 4; ++it) {
    int s = it * 16 + (tid >> 4);
    int c = (tid & 15) * 4;
    long t = ibase + (long)(h0 + (s >> 3)) * Ww + (w0c + (s & 7));
    *(float4*)(sA + s * STR + c) = *(const float4*)(xr + t * 64 + c);
  }
  stage_w4(sW, cpw, 64, tid);
  __syncthreads();

  const int t0 = (tid & 15) * 4;
  const int o0 = (tid >> 4) * 4;
  float acc[4][4];

  // --- conv branch: convp GEMM -> sB ---
#pragma unroll
  for (int i = 0; i < 4; ++i)
#pragma unroll
    for (int j = 0; j < 4; ++j) acc[i][j] = 0.f;
  gemm64(sA, sW, acc, t0, o0);
  {
    float bj0 = cpb[o0], bj1 = cpb[o0 + 1], bj2 = cpb[o0 + 2], bj3 = cpb[o0 + 3];
#pragma unroll
    for (int i = 0; i < 4; ++i)
      *(float4*)(sB + (t0 + i) * STR + o0) =
          make_float4(acc[i][0] + bj0, acc[i][1] + bj1, acc[i][2] + bj2, acc[i][3] + bj3);
  }
  __syncthreads();

  // --- pw1 GEMM: sB -> sQ[:,0:64] ---
  stage_w4(sW, pw1w, 64, tid);
  __syncthreads();
#pragma unroll
  for (int i = 0; i < 4; ++i)
#pragma unroll
    for (int j = 0; j < 4; ++j) acc[i][j] = 0.f;
  gemm64(sB, sW, acc, t0, o0);
  {
    float bj[4];
#pragma unroll
    for (int j = 0; j < 4; ++j) bj[j] = pw1b[o0 + j];
#pragma unroll
    for (int i = 0; i < 4; ++i)
#pragma unroll
      for (int j = 0; j < 4; ++j) sQ[(t0 + i) * QSTR + o0 + j] = acc[i][j] + bj[j];
  }
  __syncthreads();

  // --- dw1 depthwise conv over s (zero-pad SAME, kernel 3): sQ[:,0:64] -> sB ---
  {
    int s = tid & 63;
    int cq = tid >> 6;
#pragma unroll
    for (int k = 0; k < 16; ++k) {
      int c = cq * 16 + k;
      float v = dw1b[c];
      float wv0 = dw1w[c * 3 + 0], wv1 = dw1w[c * 3 + 1], wv2 = dw1w[c * 3 + 2];
      if (s > 0)  v += sQ[(s - 1) * QSTR + c] * wv0;
      v += sQ[s * QSTR + c] * wv1;
      if (s < 63) v += sQ[(s + 1) * QSTR + c] * wv2;
      sB[s * STR + c] = v;
    }
  }
  __syncthreads();

  // --- tok GEMM: sB -> res (registers) ---
  stage_w4(sW, tokw, 64, tid);
  __syncthreads();
  float res[4][4];
#pragma unroll
  for (int i = 0; i < 4; ++i)
#pragma unroll
    for (int j = 0; j < 4; ++j) res[i][j] = 0.f;
  gemm64(sB, sW, res, t0, o0);
  __syncthreads();

  // --- qkv GEMM (3 chunks of 64 outs): sA -> sQ[:,0:192] ---
  for (int g = 0; g < 3; ++g) {
    stage_w4(sW, qkvw + g * 4096, 64, tid);
    __syncthreads();
#pragma unroll
    for (int i = 0; i < 4; ++i)
#pragma unroll
      for (int j = 0; j < 4; ++j) acc[i][j] = 0.f;
    gemm64(sA, sW, acc, t0, o0);
    float bj[4];
#pragma unroll
    for (int j = 0; j < 4; ++j) bj[j] = qkvb[g * 64 + o0 + j];
#pragma unroll
    for (int i = 0; i < 4; ++i)
#pragma unroll
      for (int j = 0; j < 4; ++j) sQ[(t0 + i) * QSTR + g * 64 + o0 + j] = acc[i][j] + bj[j];
    __syncthreads();
  }

  // --- per-token 4x4 head-axis attention ---
  // qkv reshaped (NH=4, 3*HD=48) then split: q=h*48+d, k=h*48+16+d, v=h*48+32+d
  {
    int s = tid & 63;
    int h = tid >> 6;
    const float* qp = sQ + s * QSTR;
    float qr[16];
#pragma unroll
    for (int d = 0; d < 16; ++d) qr[d] = qp[h * 48 + d];
    float sc[4];
#pragma unroll
    for (int g = 0; g < 4; ++g) {
      float a = 0.f;
#pragma unroll
      for (int d = 0; d < 16; ++d) a += qr[d] * qp[g * 48 + 16 + d];
      sc[g] = a * 0.25f + posb[(s * 4 + h) * 4 + g];  // HD^-0.5 = 0.25
    }
    float m = fmaxf(fmaxf(sc[0], sc[1]), fmaxf(sc[2], sc[3]));
    float e[4]; float sum = 0.f;
#pragma unroll
    for (int g = 0; g < 4; ++g) { e[g] = expf(sc[g] - m); sum += e[g]; }
    float inv = 1.0f / sum;
#pragma unroll
    for (int d = 0; d < 16; ++d) {
      float a = 0.f;
#pragma unroll
      for (int g = 0; g < 4; ++g) a += e[g] * qp[g * 48 + 32 + d];
      sB[s * STR + h * 16 + d] = a * inv;  // ao flat col = h*16+d
    }
  }
  stage_w4(sW, outw, 64, tid);  // sW free after qkv loop's trailing sync
  __syncthreads();

  // --- out GEMM: sB(ao) -> res accumulate ---
  gemm64(sB, sW, res, t0, o0);

  // --- epilogue: + out_b + tok_b, scatter back to own raster tokens ---
  {
    float bj[4];
#pragma unroll
    for (int j = 0; j < 4; ++j) bj[j] = outb[o0 + j] + tokb[o0 + j];
#pragma unroll
    for (int i = 0; i < 4; ++i) {
      int s = t0 + i;
      long t = ibase + (long)(h0 + (s >> 3)) * Ww + (w0c + (s & 7));
      *(float4*)(xr + t * 64 + o0) =
          make_float4(res[i][0] + bj[0], res[i][1] + bj[1], res[i][2] + bj[2], res[i][3] + bj[3]);
    }
  }
}

// ---------------- K3: x1 = x + remsa (in place over r) ; xn2 = LN2(x1) ----------------

__global__ __launch_bounds__(256) void k3_resln(const float* __restrict__ x, float* xr,
                                                float* __restrict__ xn2,
                                                const float* __restrict__ g2, const float* __restrict__ b2) {
  __shared__ float tile[64 * 65];
  __shared__ float mu[64], rs[64];
  const int tid = threadIdx.x;
  const long p0 = (long)blockIdx.x * 64;
  const int b = (int)(p0 / HW);
  const int rem = (int)(p0 - (long)b * HW);
  const int h = rem / Ww, w0 = rem - (rem / Ww) * Ww;
#pragma unroll
  for (int it = 0; it < 16; ++it) {
    int c = it * 4 + (tid >> 6);
    int wo = tid & 63;
    tile[wo * 65 + c] = x[(((long)(b * Cc + c)) * Hh + h) * Ww + w0 + wo];
  }
  __syncthreads();
  {
    int c = tid & 63;
#pragma unroll
    for (int it = 0; it < 16; ++it) {
      int p = (tid >> 6) * 16 + it;
      float v = tile[p * 65 + c] + xr[(p0 + p) * 64 + c];
      xr[(p0 + p) * 64 + c] = v;   // x1
      tile[p * 65 + c] = v;
    }
  }
  __syncthreads();
  if (tid < 64) {
    float s = 0.f, sq = 0.f;
#pragma unroll
    for (int c = 0; c < 64; ++c) { float v = tile[tid * 65 + c]; s += v; sq += v * v; }
    float m = s * (1.0f / 64.0f);
    float var = sq * (1.0f / 64.0f) - m * m;
    mu[tid] = m; rs[tid] = rsqrtf(var + 1e-5f);
  }
  __syncthreads();
  {
    int c = tid & 63;
    float gw = g2[c], gb = b2[c];
#pragma unroll
    for (int it = 0; it < 16; ++it) {
      int p = (tid >> 6) * 16 + it;
      xn2[(p0 + p) * 64 + c] = (tile[p * 65 + c] - mu[p]) * rs[p] * gw + gb;
    }
  }
}

// ---------------- K4: LeFF 1x1 conv (no bias): y = xn2 @ pw_w^T ----------------

__global__ __launch_bounds__(256) void k4_pw(const float* __restrict__ xn2, float* __restrict__ y,
                                             const float* __restrict__ lpw) {
  __shared__ float sA[64 * STR];
  __shared__ float sW[64 * STR];
  const int tid = threadIdx.x;
  const long p0 = (long)blockIdx.x * 64;
  load_tile(sA, xn2 + p0 * 64, tid);
  stage_w4(sW, lpw, 64, tid);
  __syncthreads();
  const int t0 = (tid & 15) * 4, o0 = (tid >> 4) * 4;
  float acc[4][4];
#pragma unroll
  for (int i = 0; i < 4; ++i)
#pragma unroll
    for (int j = 0; j < 4; ++j) acc[i][j] = 0.f;
  gemm64(sA, sW, acc, t0, o0);
#pragma unroll
  for (int i = 0; i < 4; ++i)
    *(float4*)(y + (p0 + t0 + i) * 64 + o0) = make_float4(acc[i][0], acc[i][1], acc[i][2], acc[i][3]);
}

// ---------------- K5: LeFF 3x3 depthwise conv + bias ----------------

__global__ __launch_bounds__(256) void k5_dw(const float* __restrict__ y, float* __restrict__ z,
                                             const float* __restrict__ dww, const float* __restrict__ dwb) {
  const int tid = threadIdx.x;
  const long p0 = (long)blockIdx.x * 64;
  const int b = (int)(p0 / HW);
  const int rem = (int)(p0 - (long)b * HW);
  const int h = rem / Ww, w0 = rem - (rem / Ww) * Ww;
  const int c = tid & 63;
  const int pq = tid >> 6;
  float w9[9];
#pragma unroll
  for (int k = 0; k < 9; ++k) w9[k] = dww[c * 9 + k];
  const float bias = dwb[c];
  const long cbase = (long)b * HW;
#pragma unroll
  for (int it = 0; it < 16; ++it) {
    int p = it * 4 + pq;
    int w = w0 + p;
    float acc = bias;
#pragma unroll
    for (int dy = 0; dy < 3; ++dy) {
      int hh = h + dy - 1;
      if (hh < 0 || hh > Hh - 1) continue;
#pragma unroll
      for (int dx = 0; dx < 3; ++dx) {
        int ww = w + dx - 1;
        if (ww < 0 || ww > Ww - 1) continue;
        acc += y[(cbase + (long)hh * Ww + ww) * 64 + c] * w9[dy * 3 + dx];
      }
    }
    z[(p0 + p) * 64 + c] = acc;
  }
}

// ---------------- K6: fc1+GELU+fc2 + residual + transpose-store to BCHW ----------------

__global__ __launch_bounds__(256) void k6_mlp(const float* __restrict__ z, const float* __restrict__ x1,
                                              float* __restrict__ out,
                                              const float* __restrict__ f1w, const float* __restrict__ f1b,
                                              const float* __restrict__ f2w, const float* __restrict__ f2b) {
  __shared__ float sA[64 * STR];
  __shared__ float sW[64 * STR];
  __shared__ float sB[64 * STR];
  const int tid = threadIdx.x;
  const long p0 = (long)blockIdx.x * 64;
  load_tile(sA, z + p0 * 64, tid);
  const int t0 = (tid & 15) * 4, o0 = (tid >> 4) * 4;
  float res[4][4];
#pragma unroll
  for (int i = 0; i < 4; ++i)
#pragma unroll
    for (int j = 0; j < 4; ++j) res[i][j] = 0.f;

  for (int jc = 0; jc < 4; ++jc) {
    stage_w4(sW, f1w + jc * 4096, 64, tid);
    __syncthreads();
    float acc[4][4];
#pragma unroll
    for (int i = 0; i < 4; ++i)
#pragma unroll
      for (int j = 0; j < 4; ++j) acc[i][j] = 0.f;
    gemm64(sA, sW, acc, t0, o0);
    {
      float bj[4];
#pragma unroll
      for (int j = 0; j < 4; ++j) bj[j] = f1b[jc * 64 + o0 + j];
#pragma unroll
      for (int i = 0; i < 4; ++i)
        *(float4*)(sB + (t0 + i) * STR + o0) =
            make_float4(gelu_exact(acc[i][0] + bj[0]), gelu_exact(acc[i][1] + bj[1]),
                        gelu_exact(acc[i][2] + bj[2]), gelu_exact(acc[i][3] + bj[3]));
    }
    __syncthreads();
    stage_w4(sW, f2w + jc * 64, 256, tid);  // fc2 chunk: cols jc*64..jc*64+63 of (64,256)
    __syncthreads();
    gemm64(sB, sW, res, t0, o0);
    __syncthreads();
  }

  // epilogue: + fc2_b + x1, stage into sA, then transposed store to BCHW
  {
    float bj[4];
#pragma unroll
    for (int j = 0; j < 4; ++j) bj[j] = f2b[o0 + j];
#pragma unroll
    for (int i = 0; i < 4; ++i) {
      float4 xv = *(const float4*)(x1 + (p0 + t0 + i) * 64 + o0);
      *(float4*)(sA + (t0 + i) * STR + o0) =
          make_float4(res[i][0] + bj[0] + xv.x, res[i][1] + bj[1] + xv.y,
                      res[i][2] + bj[2] + xv.z, res[i][3] + bj[3] + xv.w);
    }
  }
  __syncthreads();
  const int b = (int)(p0 / HW);
  const int rem = (int)(p0 - (long)b * HW);
  const int h = rem / Ww, w0 = rem - (rem / Ww) * Ww;
#pragma unroll
  for (int it = 0; it < 16; ++it) {
    int c = it * 4 + (tid >> 6);
    int wo = tid & 63;
    out[(((long)(b * Cc + c)) * Hh + h) * Ww + w0 + wo] = sA[wo * STR + c];
  }
}

// ---------------- launch ----------------

extern "C" void kernel_launch(void* const* d_in, const int* in_sizes, int n_in,
                              void* d_out, int out_size, void* d_ws, size_t ws_size,
                              hipStream_t stream) {
  const float* x    = (const float*)d_in[0];
  const float* n1w  = (const float*)d_in[1];
  const float* n1b  = (const float*)d_in[2];
  const float* qkvw = (const float*)d_in[3];
  const float* qkvb = (const float*)d_in[4];
  const float* posb = (const float*)d_in[5];
  const float* outw = (const float*)d_in[6];
  const float* outb = (const float*)d_in[7];
  const float* cpw  = (const float*)d_in[8];
  const float* cpb  = (const float*)d_in[9];
  const float* pw1w = (const float*)d_in[10];
  const float* pw1b = (const float*)d_in[11];
  const float* dw1w = (const float*)d_in[12];
  const float* dw1b = (const float*)d_in[13];
  const float* tokw = (const float*)d_in[14];
  const float* tokb = (const float*)d_in[15];
  const float* n2w  = (const float*)d_in[16];
  const float* n2b  = (const float*)d_in[17];
  const float* lpw  = (const float*)d_in[18];
  const float* ldw  = (const float*)d_in[19];
  const float* ldb  = (const float*)d_in[20];
  const float* f1w  = (const float*)d_in[21];
  const float* f1b  = (const float*)d_in[22];
  const float* f2w  = (const float*)d_in[23];
  const float* f2b  = (const float*)d_in[24];
  float* out = (float*)d_out;

  float* bufA = (float*)d_ws;                       // xn -> remsa -> x1
  float* bufB = bufA + (size_t)Tt * 64;             // xn2 -> z
  // y lives in d_out as scratch between K4 and K5 (fully overwritten by K6)

  dim3 blk(256), grid(Tt / 64);  // 4608

  k1_ln<<<grid, blk, 0, stream>>>(x, bufA, n1w, n1b);
  k2_remsa<<<grid, blk, 0, stream>>>(bufA, qkvw, qkvb, posb, outw, outb, cpw, cpb,
                                     pw1w, pw1b, dw1w, dw1b, tokw, tokb);
  k3_resln<<<grid, blk, 0, stream>>>(x, bufA, bufB, n2w, n2b);
  k4_pw<<<grid, blk, 0, stream>>>(bufB, out, lpw);
  k5_dw<<<grid, blk, 0, stream>>>(out, bufB, ldw, ldb);
  k6_mlp<<<grid, blk, 0, stream>>>(bufB, bufA, out, f1w, f1b, f2w, f2b);
}

// Round 2
// 423.227 us; speedup vs baseline: 5.7738x; 5.7738x over previous
//
#include <hip/hip_runtime.h>
#include <math.h>

#define Bn 2
#define Cc 64
#define Hh 384
#define Ww 384
#define HW (Hh*Ww)          // 147456
#define Tt (Bn*HW)          // 294912 tokens
#define QSTR 193            // f32 LDS stride for qkv scratch (193%32==1 -> conflict-free scalar)

using f32x4  = __attribute__((ext_vector_type(4))) float;
using bf16x8 = __attribute__((ext_vector_type(8))) short;

// ---------------- helpers ----------------

__device__ __forceinline__ unsigned short f2bf_u(float f) {
  union { float f; unsigned u; } v; v.f = f;
  return (unsigned short)((v.u + 0x7FFFu + ((v.u >> 16) & 1u)) >> 16);
}

// stage a 64x64 f32 tile (row stride rs) -> LDS bf16 [64][64], XOR-swizzled
__device__ __forceinline__ void stage_wtile(char* dst, const float* __restrict__ g, int rs, int tid) {
#pragma unroll
  for (int half = 0; half < 2; ++half) {
    int q = tid + half * 256;
    int row = q >> 3, ks = q & 7;
    const float* gp = g + (long)row * rs + ks * 8;
    float4 a = *(const float4*)gp;
    float4 b = *(const float4*)(gp + 4);
    bf16x8 o;
    o[0] = (short)f2bf_u(a.x); o[1] = (short)f2bf_u(a.y);
    o[2] = (short)f2bf_u(a.z); o[3] = (short)f2bf_u(a.w);
    o[4] = (short)f2bf_u(b.x); o[5] = (short)f2bf_u(b.y);
    o[6] = (short)f2bf_u(b.z); o[7] = (short)f2bf_u(b.w);
    *(bf16x8*)(dst + row * 128 + ((ks * 16) ^ ((row & 7) << 4))) = o;
  }
}

// 64x64x64 GEMM: out rows 16*wid..16*wid+15, all 64 cols. acc[nt] accumulates.
__device__ __forceinline__ void mfma64(const char* sA, const char* sB, int wid, int lane, f32x4 acc[4]) {
  const int r = lane & 15, kq = lane >> 4;
#pragma unroll
  for (int kh = 0; kh < 2; ++kh) {
    const int arow = wid * 16 + r;
    bf16x8 af = *(const bf16x8*)(sA + arow * 128 + ((kh * 64 + kq * 16) ^ ((arow & 7) << 4)));
#pragma unroll
    for (int nt = 0; nt < 4; ++nt) {
      const int brow = nt * 16 + r;
      bf16x8 bfv = *(const bf16x8*)(sB + brow * 128 + ((kh * 64 + kq * 16) ^ ((brow & 7) << 4)));
      acc[nt] = __builtin_amdgcn_mfma_f32_16x16x32_bf16(af, bfv, acc[nt], 0, 0, 0);
    }
  }
}

// MFMA acc (+bias) -> bf16 LDS tile (swizzled)
__device__ __forceinline__ void acc_to_tile(char* dst, const f32x4 acc[4], int wid, int lane,
                                            const float* __restrict__ bias) {
  const int cbase = lane & 15;
  const int rbase = wid * 16 + (lane >> 4) * 4;
#pragma unroll
  for (int nt = 0; nt < 4; ++nt) {
    const int col = nt * 16 + cbase;
    const float bv = bias[col];
#pragma unroll
    for (int reg = 0; reg < 4; ++reg) {
      const int row = rbase + reg;
      *(unsigned short*)(dst + row * 128 + ((col * 2) ^ ((row & 7) << 4))) = f2bf_u(acc[nt][reg] + bv);
    }
  }
}

__device__ __forceinline__ float gelu_exact(float v) {
  return 0.5f * v * (1.0f + erff(v * 0.70710678118654752f));
}

// ---------------- K1: channel LayerNorm + transpose to token-major ----------------

__global__ __launch_bounds__(256) void k1_ln(const float* __restrict__ x, float* __restrict__ xn,
                                             const float* __restrict__ g1, const float* __restrict__ b1) {
  __shared__ float tile[64 * 65];
  __shared__ float mu[64], rs[64];
  const int tid = threadIdx.x;
  const long p0 = (long)blockIdx.x * 64;
  const int b = (int)(p0 / HW);
  const int rem = (int)(p0 - (long)b * HW);
  const int h = rem / Ww, w0 = rem - (rem / Ww) * Ww;
#pragma unroll
  for (int it = 0; it < 16; ++it) {
    int c = it * 4 + (tid >> 6);
    int wo = tid & 63;
    tile[wo * 65 + c] = x[(((long)(b * Cc + c)) * Hh + h) * Ww + w0 + wo];
  }
  __syncthreads();
  if (tid < 64) {
    float s = 0.f, sq = 0.f;
#pragma unroll
    for (int c = 0; c < 64; ++c) { float v = tile[tid * 65 + c]; s += v; sq += v * v; }
    float m = s * (1.0f / 64.0f);
    float var = sq * (1.0f / 64.0f) - m * m;
    mu[tid] = m; rs[tid] = rsqrtf(var + 1e-5f);
  }
  __syncthreads();
  {
    int c = tid & 63;
    float gw = g1[c], gb = b1[c];
#pragma unroll
    for (int it = 0; it < 16; ++it) {
      int p = (tid >> 6) * 16 + it;
      xn[(p0 + p) * 64 + c] = (tile[p * 65 + c] - mu[p]) * rs[p] * gw + gb;
    }
  }
}

// ---------------- K2: fused per-window REMSA (MFMA) ----------------

__global__ __launch_bounds__(256, 2) void k2_remsa(
    float* xr,
    const float* __restrict__ qkvw, const float* __restrict__ qkvb,
    const float* __restrict__ posb,
    const float* __restrict__ outw, const float* __restrict__ outb,
    const float* __restrict__ cpw, const float* __restrict__ cpb,
    const float* __restrict__ pw1w, const float* __restrict__ pw1b,
    const float* __restrict__ dw1w, const float* __restrict__ dw1b,
    const float* __restrict__ tokw, const float* __restrict__ tokb) {
  __shared__ char sX[8192];          // LN'd window input (bf16, swizzled)
  __shared__ char sW[8192];          // streamed weight tile (bf16, swizzled)
  __shared__ char sT[8192];          // intermediate operand tile (bf16, swizzled)
  __shared__ float sQ[64 * QSTR];    // f32 scratch: pw1-out, then qkv (192 cols)
  const int tid = threadIdx.x;
  const int lane = tid & 63, wid = tid >> 6;
  const int blk = blockIdx.x;
  const int b = blk / 2304;
  const int rr = blk - b * 2304;
  const int wy = rr / 48, wx = rr - (rr / 48) * 48;
  const int h0 = wy * 8, w0c = wx * 8;
  const long ibase = (long)b * HW;

  // stage window tile -> sX (bf16)
#pragma unroll
  for (int half = 0; half < 2; ++half) {
    int q = tid + half * 256;
    int row = q >> 3, ks = q & 7;
    long t = ibase + (long)(h0 + (row >> 3)) * Ww + (w0c + (row & 7));
    const float* gp = xr + t * 64 + ks * 8;
    float4 a = *(const float4*)gp;
    float4 bb = *(const float4*)(gp + 4);
    bf16x8 o;
    o[0] = (short)f2bf_u(a.x);  o[1] = (short)f2bf_u(a.y);
    o[2] = (short)f2bf_u(a.z);  o[3] = (short)f2bf_u(a.w);
    o[4] = (short)f2bf_u(bb.x); o[5] = (short)f2bf_u(bb.y);
    o[6] = (short)f2bf_u(bb.z); o[7] = (short)f2bf_u(bb.w);
    *(bf16x8*)(sX + row * 128 + ((ks * 16) ^ ((row & 7) << 4))) = o;
  }
  stage_wtile(sW, cpw, 64, tid);
  __syncthreads();

  const int cbase = lane & 15;
  const int rbase = wid * 16 + (lane >> 4) * 4;
  f32x4 acc[4];

  // --- GEMM1: convp -> sT ---
#pragma unroll
  for (int nt = 0; nt < 4; ++nt) acc[nt] = (f32x4){0.f, 0.f, 0.f, 0.f};
  mfma64(sX, sW, wid, lane, acc);
  acc_to_tile(sT, acc, wid, lane, cpb);
  __syncthreads();

  // --- GEMM2: pw1: sT -> sQ (f32) ---
  stage_wtile(sW, pw1w, 64, tid);
  __syncthreads();
#pragma unroll
  for (int nt = 0; nt < 4; ++nt) acc[nt] = (f32x4){0.f, 0.f, 0.f, 0.f};
  mfma64(sT, sW, wid, lane, acc);
#pragma unroll
  for (int nt = 0; nt < 4; ++nt) {
    const int col = nt * 16 + cbase;
    const float bv = pw1b[col];
#pragma unroll
    for (int reg = 0; reg < 4; ++reg) sQ[(rbase + reg) * QSTR + col] = acc[nt][reg] + bv;
  }
  __syncthreads();

  // --- dw1 depthwise conv over s (+ stage tokw concurrently) ---
  {
    int c = tid & 63;
    int sbase = (tid >> 6) * 16;
    float wv0 = dw1w[c * 3 + 0], wv1 = dw1w[c * 3 + 1], wv2 = dw1w[c * 3 + 2];
    float bia = dw1b[c];
#pragma unroll
    for (int k = 0; k < 16; ++k) {
      int s = sbase + k;
      float v = bia + sQ[s * QSTR + c] * wv1;
      if (s > 0)  v += sQ[(s - 1) * QSTR + c] * wv0;
      if (s < 63) v += sQ[(s + 1) * QSTR + c] * wv2;
      *(unsigned short*)(sT + s * 128 + ((c * 2) ^ ((s & 7) << 4))) = f2bf_u(v);
    }
  }
  stage_wtile(sW, tokw, 64, tid);
  __syncthreads();

  // --- GEMM3: tok: sT -> res (registers) ---
  f32x4 res[4];
#pragma unroll
  for (int nt = 0; nt < 4; ++nt) res[nt] = (f32x4){0.f, 0.f, 0.f, 0.f};
  mfma64(sT, sW, wid, lane, res);
  __syncthreads();

  // --- qkv GEMMs -> sQ f32 (192 cols) ---
  for (int g = 0; g < 3; ++g) {
    stage_wtile(sW, qkvw + g * 4096, 64, tid);
    __syncthreads();
#pragma unroll
    for (int nt = 0; nt < 4; ++nt) acc[nt] = (f32x4){0.f, 0.f, 0.f, 0.f};
    mfma64(sX, sW, wid, lane, acc);
#pragma unroll
    for (int nt = 0; nt < 4; ++nt) {
      const int col = nt * 16 + cbase;
      const float bv = qkvb[g * 64 + col];
#pragma unroll
      for (int reg = 0; reg < 4; ++reg)
        sQ[(rbase + reg) * QSTR + g * 64 + col] = acc[nt][reg] + bv;
    }
    __syncthreads();
  }

  // --- per-token 4x4 head-axis attention: sQ -> sT (bf16) ---
  stage_wtile(sW, outw, 64, tid);
  {
    int s = tid >> 2;
    int h = tid & 3;
    const float* qp = sQ + s * QSTR;
    float qr[16];
#pragma unroll
    for (int d = 0; d < 16; ++d) qr[d] = qp[h * 48 + d];
    float sc[4];
#pragma unroll
    for (int g = 0; g < 4; ++g) {
      float a = 0.f;
#pragma unroll
      for (int d = 0; d < 16; ++d) a += qr[d] * qp[g * 48 + 16 + d];
      sc[g] = a * 0.25f + posb[(s * 4 + h) * 4 + g];
    }
    float m = fmaxf(fmaxf(sc[0], sc[1]), fmaxf(sc[2], sc[3]));
    float e[4]; float sum = 0.f;
#pragma unroll
    for (int g = 0; g < 4; ++g) { e[g] = expf(sc[g] - m); sum += e[g]; }
    float inv = 1.0f / sum;
#pragma unroll
    for (int d = 0; d < 16; ++d) {
      float a = 0.f;
#pragma unroll
      for (int g = 0; g < 4; ++g) a += e[g] * qp[g * 48 + 32 + d];
      int col = h * 16 + d;
      *(unsigned short*)(sT + s * 128 + ((col * 2) ^ ((s & 7) << 4))) = f2bf_u(a * inv);
    }
  }
  __syncthreads();

  // --- GEMM4: out-proj, accumulate into res; epilogue store ---
  mfma64(sT, sW, wid, lane, res);
#pragma unroll
  for (int nt = 0; nt < 4; ++nt) {
    const int col = nt * 16 + cbase;
    const float bv = outb[col] + tokb[col];
#pragma unroll
    for (int reg = 0; reg < 4; ++reg) {
      const int row = rbase + reg;
      long t = ibase + (long)(h0 + (row >> 3)) * Ww + (w0c + (row & 7));
      xr[t * 64 + col] = res[nt][reg] + bv;
    }
  }
}

// ---------------- K3: x1 = x + remsa ; xn2 = LN2(x1) ----------------

__global__ __launch_bounds__(256) void k3_resln(const float* __restrict__ x, float* xr,
                                                float* __restrict__ xn2,
                                                const float* __restrict__ g2, const float* __restrict__ b2) {
  __shared__ float tile[64 * 65];
  __shared__ float mu[64], rs[64];
  const int tid = threadIdx.x;
  const long p0 = (long)blockIdx.x * 64;
  const int b = (int)(p0 / HW);
  const int rem = (int)(p0 - (long)b * HW);
  const int h = rem / Ww, w0 = rem - (rem / Ww) * Ww;
#pragma unroll
  for (int it = 0; it < 16; ++it) {
    int c = it * 4 + (tid >> 6);
    int wo = tid & 63;
    tile[wo * 65 + c] = x[(((long)(b * Cc + c)) * Hh + h) * Ww + w0 + wo];
  }
  __syncthreads();
  {
    int c = tid & 63;
#pragma unroll
    for (int it = 0; it < 16; ++it) {
      int p = (tid >> 6) * 16 + it;
      float v = tile[p * 65 + c] + xr[(p0 + p) * 64 + c];
      xr[(p0 + p) * 64 + c] = v;
      tile[p * 65 + c] = v;
    }
  }
  __syncthreads();
  if (tid < 64) {
    float s = 0.f, sq = 0.f;
#pragma unroll
    for (int c = 0; c < 64; ++c) { float v = tile[tid * 65 + c]; s += v; sq += v * v; }
    float m = s * (1.0f / 64.0f);
    float var = sq * (1.0f / 64.0f) - m * m;
    mu[tid] = m; rs[tid] = rsqrtf(var + 1e-5f);
  }
  __syncthreads();
  {
    int c = tid & 63;
    float gw = g2[c], gb = b2[c];
#pragma unroll
    for (int it = 0; it < 16; ++it) {
      int p = (tid >> 6) * 16 + it;
      xn2[(p0 + p) * 64 + c] = (tile[p * 65 + c] - mu[p]) * rs[p] * gw + gb;
    }
  }
}

// ---------------- K4: LeFF 1x1 conv (no bias), MFMA ----------------

__global__ __launch_bounds__(256) void k4_pw(const float* __restrict__ xn2, float* __restrict__ y,
                                             const float* __restrict__ lpw) {
  __shared__ char sA[8192];
  __shared__ char sW[8192];
  const int tid = threadIdx.x;
  const int lane = tid & 63, wid = tid >> 6;
  const long p0 = (long)blockIdx.x * 64;
  stage_wtile(sA, xn2 + p0 * 64, 64, tid);
  stage_wtile(sW, lpw, 64, tid);
  __syncthreads();
  f32x4 acc[4];
#pragma unroll
  for (int nt = 0; nt < 4; ++nt) acc[nt] = (f32x4){0.f, 0.f, 0.f, 0.f};
  mfma64(sA, sW, wid, lane, acc);
  const int cbase = lane & 15;
  const int rbase = wid * 16 + (lane >> 4) * 4;
#pragma unroll
  for (int nt = 0; nt < 4; ++nt) {
    const int col = nt * 16 + cbase;
#pragma unroll
    for (int reg = 0; reg < 4; ++reg)
      y[(p0 + rbase + reg) * 64 + col] = acc[nt][reg];
  }
}

// ---------------- K5: LeFF 3x3 depthwise conv + bias ----------------

__global__ __launch_bounds__(256) void k5_dw(const float* __restrict__ y, float* __restrict__ z,
                                             const float* __restrict__ dww, const float* __restrict__ dwb) {
  const int tid = threadIdx.x;
  const long p0 = (long)blockIdx.x * 64;
  const int b = (int)(p0 / HW);
  const int rem = (int)(p0 - (long)b * HW);
  const int h = rem / Ww, w0 = rem - (rem / Ww) * Ww;
  const int c = tid & 63;
  const int pq = tid >> 6;
  float w9[9];
#pragma unroll
  for (int k = 0; k < 9; ++k) w9[k] = dww[c * 9 + k];
  const float bias = dwb[c];
  const long cbase = (long)b * HW;
#pragma unroll
  for (int it = 0; it < 16; ++it) {
    int p = it * 4 + pq;
    int w = w0 + p;
    float acc = bias;
#pragma unroll
    for (int dy = 0; dy < 3; ++dy) {
      int hh = h + dy - 1;
      if (hh < 0 || hh > Hh - 1) continue;
#pragma unroll
      for (int dx = 0; dx < 3; ++dx) {
        int ww = w + dx - 1;
        if (ww < 0 || ww > Ww - 1) continue;
        acc += y[(cbase + (long)hh * Ww + ww) * 64 + c] * w9[dy * 3 + dx];
      }
    }
    z[(p0 + p) * 64 + c] = acc;
  }
}

// ---------------- K6: fc1+GELU+fc2 + residual + transpose-store, MFMA ----------------

__global__ __launch_bounds__(256) void k6_mlp(const float* __restrict__ z, const float* __restrict__ x1,
                                              float* __restrict__ out,
                                              const float* __restrict__ f1w, const float* __restrict__ f1b,
                                              const float* __restrict__ f2w, const float* __restrict__ f2b) {
  __shared__ char sZ[8192];
  __shared__ char sW[8192];
  __shared__ char sH[8192];
  __shared__ float sO[64 * 65];
  const int tid = threadIdx.x;
  const int lane = tid & 63, wid = tid >> 6;
  const long p0 = (long)blockIdx.x * 64;
  stage_wtile(sZ, z + p0 * 64, 64, tid);
  const int cbase = lane & 15;
  const int rbase = wid * 16 + (lane >> 4) * 4;
  f32x4 res[4];
#pragma unroll
  for (int nt = 0; nt < 4; ++nt) res[nt] = (f32x4){0.f, 0.f, 0.f, 0.f};

  for (int jc = 0; jc < 4; ++jc) {
    stage_wtile(sW, f1w + jc * 4096, 64, tid);
    __syncthreads();
    f32x4 acc[4];
#pragma unroll
    for (int nt = 0; nt < 4; ++nt) acc[nt] = (f32x4){0.f, 0.f, 0.f, 0.f};
    mfma64(sZ, sW, wid, lane, acc);
    // gelu(acc + f1b) -> sH (bf16)
#pragma unroll
    for (int nt = 0; nt < 4; ++nt) {
      const int col = nt * 16 + cbase;
      const float bv = f1b[jc * 64 + col];
#pragma unroll
      for (int reg = 0; reg < 4; ++reg) {
        const int row = rbase + reg;
        *(unsigned short*)(sH + row * 128 + ((col * 2) ^ ((row & 7) << 4))) =
            f2bf_u(gelu_exact(acc[nt][reg] + bv));
      }
    }
    __syncthreads();
    stage_wtile(sW, f2w + jc * 64, 256, tid);
    __syncthreads();
    mfma64(sH, sW, wid, lane, res);
    __syncthreads();
  }

  // epilogue: + f2b + x1 -> sO, then transposed store to BCHW
#pragma unroll
  for (int nt = 0; nt < 4; ++nt) {
    const int col = nt * 16 + cbase;
    const float bv = f2b[col];
#pragma unroll
    for (int reg = 0; reg < 4; ++reg) {
      const int row = rbase + reg;
      sO[row * 65 + col] = res[nt][reg] + bv + x1[(p0 + row) * 64 + col];
    }
  }
  __syncthreads();
  const int b = (int)(p0 / HW);
  const int rem = (int)(p0 - (long)b * HW);
  const int h = rem / Ww, w0 = rem - (rem / Ww) * Ww;
#pragma unroll
  for (int it = 0; it < 16; ++it) {
    int c = it * 4 + (tid >> 6);
    int wo = tid & 63;
    out[(((long)(b * Cc + c)) * Hh + h) * Ww + w0 + wo] = sO[wo * 65 + c];
  }
}

// ---------------- launch ----------------

extern "C" void kernel_launch(void* const* d_in, const int* in_sizes, int n_in,
                              void* d_out, int out_size, void* d_ws, size_t ws_size,
                              hipStream_t stream) {
  const float* x    = (const float*)d_in[0];
  const float* n1w  = (const float*)d_in[1];
  const float* n1b  = (const float*)d_in[2];
  const float* qkvw = (const float*)d_in[3];
  const float* qkvb = (const float*)d_in[4];
  const float* posb = (const float*)d_in[5];
  const float* outw = (const float*)d_in[6];
  const float* outb = (const float*)d_in[7];
  const float* cpw  = (const float*)d_in[8];
  const float* cpb  = (const float*)d_in[9];
  const float* pw1w = (const float*)d_in[10];
  const float* pw1b = (const float*)d_in[11];
  const float* dw1w = (const float*)d_in[12];
  const float* dw1b = (const float*)d_in[13];
  const float* tokw = (const float*)d_in[14];
  const float* tokb = (const float*)d_in[15];
  const float* n2w  = (const float*)d_in[16];
  const float* n2b  = (const float*)d_in[17];
  const float* lpw  = (const float*)d_in[18];
  const float* ldw  = (const float*)d_in[19];
  const float* ldb  = (const float*)d_in[20];
  const float* f1w  = (const float*)d_in[21];
  const float* f1b  = (const float*)d_in[22];
  const float* f2w  = (const float*)d_in[23];
  const float* f2b  = (const float*)d_in[24];
  float* out = (float*)d_out;

  float* bufA = (float*)d_ws;                       // xn -> remsa -> x1
  float* bufB = bufA + (size_t)Tt * 64;             // xn2 -> z
  // y lives in d_out as scratch between K4 and K5 (fully overwritten by K6)

  dim3 blk(256), grid(Tt / 64);  // 4608

  k1_ln<<<grid, blk, 0, stream>>>(x, bufA, n1w, n1b);
  k2_remsa<<<grid, blk, 0, stream>>>(bufA, qkvw, qkvb, posb, outw, outb, cpw, cpb,
                                     pw1w, pw1b, dw1w, dw1b, tokw, tokb);
  k3_resln<<<grid, blk, 0, stream>>>(x, bufA, bufB, n2w, n2b);
  k4_pw<<<grid, blk, 0, stream>>>(bufB, out, lpw);
  k5_dw<<<grid, blk, 0, stream>>>(out, bufB, ldw, ldb);
  k6_mlp<<<grid, blk, 0, stream>>>(bufB, bufA, out, f1w, f1b, f2w, f2b);
}

// Round 3
// 263.608 us; speedup vs baseline: 9.2699x; 1.6055x over previous
//
#include <hip/hip_runtime.h>
#include <math.h>

#define Bn 2
#define Cc 64
#define Hh 384
#define Ww 384
#define HW (Hh*Ww)          // 147456
#define Tt (Bn*HW)          // 294912 tokens
#define QSTR 193            // ushort stride for qkv scratch

using f32x4  = __attribute__((ext_vector_type(4))) float;
using bf16x8 = __attribute__((ext_vector_type(8))) short;

// ---------------- helpers ----------------

__device__ __forceinline__ unsigned short f2bf_u(float f) {
  union { float f; unsigned u; } v; v.f = f;
  return (unsigned short)((v.u + 0x7FFFu + ((v.u >> 16) & 1u)) >> 16);
}
__device__ __forceinline__ float bf2f(unsigned short u) {
  union { unsigned u; float f; } v; v.u = ((unsigned)u) << 16;
  return v.f;
}

// stage a 64x64 f32 tile (row stride rs) -> LDS bf16 [64][64], XOR-swizzled
__device__ __forceinline__ void stage_wtile(char* dst, const float* __restrict__ g, int rs, int tid) {
#pragma unroll
  for (int half = 0; half < 2; ++half) {
    int q = tid + half * 256;
    int row = q >> 3, ks = q & 7;
    const float* gp = g + (long)row * rs + ks * 8;
    float4 a = *(const float4*)gp;
    float4 b = *(const float4*)(gp + 4);
    bf16x8 o;
    o[0] = (short)f2bf_u(a.x); o[1] = (short)f2bf_u(a.y);
    o[2] = (short)f2bf_u(a.z); o[3] = (short)f2bf_u(a.w);
    o[4] = (short)f2bf_u(b.x); o[5] = (short)f2bf_u(b.y);
    o[6] = (short)f2bf_u(b.z); o[7] = (short)f2bf_u(b.w);
    *(bf16x8*)(dst + row * 128 + ((ks * 16) ^ ((row & 7) << 4))) = o;
  }
}

// 64x64x64 GEMM: out rows 16*wid..16*wid+15, all 64 cols, acc accumulates
__device__ __forceinline__ void mfma64(const char* sA, const char* sB, int wid, int lane, f32x4 acc[4]) {
  const int r = lane & 15, kq = lane >> 4;
#pragma unroll
  for (int kh = 0; kh < 2; ++kh) {
    const int arow = wid * 16 + r;
    bf16x8 af = *(const bf16x8*)(sA + arow * 128 + ((kh * 64 + kq * 16) ^ ((arow & 7) << 4)));
#pragma unroll
    for (int nt = 0; nt < 4; ++nt) {
      const int brow = nt * 16 + r;
      bf16x8 bfv = *(const bf16x8*)(sB + brow * 128 + ((kh * 64 + kq * 16) ^ ((brow & 7) << 4)));
      acc[nt] = __builtin_amdgcn_mfma_f32_16x16x32_bf16(af, bfv, acc[nt], 0, 0, 0);
    }
  }
}

__device__ __forceinline__ void acc_to_tile(char* dst, const f32x4 acc[4], int wid, int lane,
                                            const float* __restrict__ bias) {
  const int cbase = lane & 15;
  const int rbase = wid * 16 + (lane >> 4) * 4;
#pragma unroll
  for (int nt = 0; nt < 4; ++nt) {
    const int col = nt * 16 + cbase;
    const float bv = bias[col];
#pragma unroll
    for (int reg = 0; reg < 4; ++reg) {
      const int row = rbase + reg;
      *(unsigned short*)(dst + row * 128 + ((col * 2) ^ ((row & 7) << 4))) = f2bf_u(acc[nt][reg] + bv);
    }
  }
}

__device__ __forceinline__ float gelu_exact(float v) {
  return 0.5f * v * (1.0f + erff(v * 0.70710678118654752f));
}

// ================= K_A: LN1 + REMSA + residual + LN2 + pw GEMM =================
// per 8x8 window block: reads x (BCHW), writes x1 (f32 token-major), y (bf16 token-major)

__global__ __launch_bounds__(256, 2) void kA(
    const float* __restrict__ x, float* __restrict__ x1g, unsigned short* __restrict__ yg,
    const float* __restrict__ n1w, const float* __restrict__ n1b,
    const float* __restrict__ qkvw, const float* __restrict__ qkvb,
    const float* __restrict__ posb,
    const float* __restrict__ outw, const float* __restrict__ outb,
    const float* __restrict__ cpw, const float* __restrict__ cpb,
    const float* __restrict__ pw1w, const float* __restrict__ pw1b,
    const float* __restrict__ dw1w, const float* __restrict__ dw1b,
    const float* __restrict__ tokw, const float* __restrict__ tokb,
    const float* __restrict__ n2w, const float* __restrict__ n2b,
    const float* __restrict__ lpw) {
  __shared__ char sX[8192];               // bf16 operand tile (LN1'd x, later LN2'd x1)
  __shared__ char sW[8192];               // streamed weight tile
  __shared__ char sT[8192];               // intermediate tile / y staging
  __shared__ float sLN[64 * 65];          // raw x (f32), later x1
  __shared__ unsigned short sQh[64 * QSTR]; // bf16 scratch: pw1-out, qkv
  __shared__ float mu[64], rsd[64];

  const int tid = threadIdx.x;
  const int lane = tid & 63, wid = tid >> 6;
  const int blk = blockIdx.x;
  const int b = blk / 2304;
  const int rr = blk - b * 2304;
  const int wy = rr / 48, wx = rr - (rr / 48) * 48;
  const int h0 = wy * 8, w0c = wx * 8;
  const long ibase = (long)b * HW;

  // --- phase 1: gather raw x window -> sLN [s][c], stride 65 ---
#pragma unroll
  for (int it = 0; it < 16; ++it) {
    int idx = it * 256 + tid;
    int c = idx >> 6, rem = idx & 63;
    int iy = rem >> 3, ix = rem & 7;
    sLN[(iy * 8 + ix) * 65 + c] = x[(((long)(b * Cc + c)) * Hh + h0 + iy) * Ww + w0c + ix];
  }
  __syncthreads();

  // --- LN1 stats ---
  if (tid < 64) {
    float s = 0.f, sq = 0.f;
#pragma unroll
    for (int c = 0; c < 64; ++c) { float v = sLN[tid * 65 + c]; s += v; sq += v * v; }
    float m = s * (1.0f / 64.0f);
    float var = sq * (1.0f / 64.0f) - m * m;
    mu[tid] = m; rsd[tid] = rsqrtf(var + 1e-5f);
  }
  __syncthreads();

  // --- normalize -> sX (bf16, swizzled); stage convp into sW ---
#pragma unroll
  for (int it = 0; it < 2; ++it) {
    int q = it * 256 + tid;
    int row = q >> 3, c8 = q & 7;
    float m = mu[row], r = rsd[row];
    bf16x8 o;
#pragma unroll
    for (int j = 0; j < 8; ++j) {
      int c = c8 * 8 + j;
      o[j] = (short)f2bf_u((sLN[row * 65 + c] - m) * r * n1w[c] + n1b[c]);
    }
    *(bf16x8*)(sX + row * 128 + ((c8 * 16) ^ ((row & 7) << 4))) = o;
  }
  stage_wtile(sW, cpw, 64, tid);
  __syncthreads();

  const int cbase = lane & 15;
  const int rbase = wid * 16 + (lane >> 4) * 4;
  f32x4 acc[4];

  // --- GEMM1: convp -> sT ---
#pragma unroll
  for (int nt = 0; nt < 4; ++nt) acc[nt] = (f32x4){0.f, 0.f, 0.f, 0.f};
  mfma64(sX, sW, wid, lane, acc);
  acc_to_tile(sT, acc, wid, lane, cpb);
  __syncthreads();

  // --- GEMM2: pw1 -> sQh[:,0:64] (bf16) ---
  stage_wtile(sW, pw1w, 64, tid);
  __syncthreads();
#pragma unroll
  for (int nt = 0; nt < 4; ++nt) acc[nt] = (f32x4){0.f, 0.f, 0.f, 0.f};
  mfma64(sT, sW, wid, lane, acc);
#pragma unroll
  for (int nt = 0; nt < 4; ++nt) {
    const int col = nt * 16 + cbase;
    const float bv = pw1b[col];
#pragma unroll
    for (int reg = 0; reg < 4; ++reg)
      sQh[(rbase + reg) * QSTR + col] = f2bf_u(acc[nt][reg] + bv);
  }
  __syncthreads();

  // --- dw1 depthwise over s -> sT; stage tokw ---
  {
    int c = tid & 63;
    int sbase = (tid >> 6) * 16;
    float wv0 = dw1w[c * 3 + 0], wv1 = dw1w[c * 3 + 1], wv2 = dw1w[c * 3 + 2];
    float bia = dw1b[c];
#pragma unroll
    for (int k = 0; k < 16; ++k) {
      int s = sbase + k;
      float v = bia + bf2f(sQh[s * QSTR + c]) * wv1;
      if (s > 0)  v += bf2f(sQh[(s - 1) * QSTR + c]) * wv0;
      if (s < 63) v += bf2f(sQh[(s + 1) * QSTR + c]) * wv2;
      *(unsigned short*)(sT + s * 128 + ((c * 2) ^ ((s & 7) << 4))) = f2bf_u(v);
    }
  }
  stage_wtile(sW, tokw, 64, tid);
  __syncthreads();

  // --- GEMM3: tok -> res ---
  f32x4 res[4];
#pragma unroll
  for (int nt = 0; nt < 4; ++nt) res[nt] = (f32x4){0.f, 0.f, 0.f, 0.f};
  mfma64(sT, sW, wid, lane, res);
  __syncthreads();

  // --- qkv GEMMs -> sQh (192 cols bf16) ---
  for (int g = 0; g < 3; ++g) {
    stage_wtile(sW, qkvw + g * 4096, 64, tid);
    __syncthreads();
#pragma unroll
    for (int nt = 0; nt < 4; ++nt) acc[nt] = (f32x4){0.f, 0.f, 0.f, 0.f};
    mfma64(sX, sW, wid, lane, acc);
#pragma unroll
    for (int nt = 0; nt < 4; ++nt) {
      const int col = nt * 16 + cbase;
      const float bv = qkvb[g * 64 + col];
#pragma unroll
      for (int reg = 0; reg < 4; ++reg)
        sQh[(rbase + reg) * QSTR + g * 64 + col] = f2bf_u(acc[nt][reg] + bv);
    }
    __syncthreads();
  }

  // --- per-token 4x4 head-axis attention -> sT; stage outw ---
  {
    int s = tid >> 2;
    int h = tid & 3;
    const unsigned short* qp = sQh + s * QSTR;
    float qr[16];
#pragma unroll
    for (int d = 0; d < 16; ++d) qr[d] = bf2f(qp[h * 48 + d]);
    float sc[4];
#pragma unroll
    for (int g = 0; g < 4; ++g) {
      float a = 0.f;
#pragma unroll
      for (int d = 0; d < 16; ++d) a += qr[d] * bf2f(qp[g * 48 + 16 + d]);
      sc[g] = a * 0.25f + posb[(s * 4 + h) * 4 + g];
    }
    float m = fmaxf(fmaxf(sc[0], sc[1]), fmaxf(sc[2], sc[3]));
    float e[4]; float sum = 0.f;
#pragma unroll
    for (int g = 0; g < 4; ++g) { e[g] = expf(sc[g] - m); sum += e[g]; }
    float inv = 1.0f / sum;
#pragma unroll
    for (int d = 0; d < 16; ++d) {
      float a = 0.f;
#pragma unroll
      for (int g = 0; g < 4; ++g) a += e[g] * bf2f(qp[g * 48 + 32 + d]);
      int col = h * 16 + d;
      *(unsigned short*)(sT + s * 128 + ((col * 2) ^ ((s & 7) << 4))) = f2bf_u(a * inv);
    }
  }
  stage_wtile(sW, outw, 64, tid);
  __syncthreads();

  // --- GEMM4: out-proj accumulate into res; x1 = raw x + remsa (into sLN) ---
  mfma64(sT, sW, wid, lane, res);
#pragma unroll
  for (int nt = 0; nt < 4; ++nt) {
    const int col = nt * 16 + cbase;
    const float bv = outb[col] + tokb[col];
#pragma unroll
    for (int reg = 0; reg < 4; ++reg) {
      const int row = rbase + reg;
      sLN[row * 65 + col] += res[nt][reg] + bv;
    }
  }
  __syncthreads();

  // --- write x1 to global; LN2 stats ---
#pragma unroll
  for (int it = 0; it < 16; ++it) {
    int idx = it * 256 + tid;
    int row = idx >> 6, c = idx & 63;
    long t = ibase + (long)(h0 + (row >> 3)) * Ww + (w0c + (row & 7));
    x1g[t * 64 + c] = sLN[row * 65 + c];
  }
  if (tid < 64) {
    float s = 0.f, sq = 0.f;
#pragma unroll
    for (int c = 0; c < 64; ++c) { float v = sLN[tid * 65 + c]; s += v; sq += v * v; }
    float m = s * (1.0f / 64.0f);
    float var = sq * (1.0f / 64.0f) - m * m;
    mu[tid] = m; rsd[tid] = rsqrtf(var + 1e-5f);
  }
  __syncthreads();

  // --- LN2 normalize -> sX; stage lpw ---
#pragma unroll
  for (int it = 0; it < 2; ++it) {
    int q = it * 256 + tid;
    int row = q >> 3, c8 = q & 7;
    float m = mu[row], r = rsd[row];
    bf16x8 o;
#pragma unroll
    for (int j = 0; j < 8; ++j) {
      int c = c8 * 8 + j;
      o[j] = (short)f2bf_u((sLN[row * 65 + c] - m) * r * n2w[c] + n2b[c]);
    }
    *(bf16x8*)(sX + row * 128 + ((c8 * 16) ^ ((row & 7) << 4))) = o;
  }
  stage_wtile(sW, lpw, 64, tid);
  __syncthreads();

  // --- GEMM5: pw (no bias) -> y (bf16), staged via sT unswizzled ---
#pragma unroll
  for (int nt = 0; nt < 4; ++nt) acc[nt] = (f32x4){0.f, 0.f, 0.f, 0.f};
  mfma64(sX, sW, wid, lane, acc);
#pragma unroll
  for (int nt = 0; nt < 4; ++nt) {
    const int col = nt * 16 + cbase;
#pragma unroll
    for (int reg = 0; reg < 4; ++reg)
      ((unsigned short*)sT)[(rbase + reg) * 64 + col] = f2bf_u(acc[nt][reg]);
  }
  __syncthreads();
#pragma unroll
  for (int it = 0; it < 2; ++it) {
    int q = it * 256 + tid;           // 512 chunks of 16B
    int s = q >> 3, c8 = q & 7;
    long t = ibase + (long)(h0 + (s >> 3)) * Ww + (w0c + (s & 7));
    *(uint4*)((char*)yg + t * 128 + c8 * 16) = *(const uint4*)(sT + q * 16);
  }
}

// ================= K_B: 3x3 depthwise + fc1+GELU+fc2 + residual + BCHW store =================
// block = 2 consecutive rows x 64 px (2 token-tiles). Reads y(bf16) halo, x1; writes out.

__global__ __launch_bounds__(256, 3) void kB(
    const unsigned short* __restrict__ yg, const float* __restrict__ x1g,
    float* __restrict__ out,
    const float* __restrict__ ldw, const float* __restrict__ ldb,
    const float* __restrict__ f1w, const float* __restrict__ f1b,
    const float* __restrict__ f2w, const float* __restrict__ f2b) {
  __shared__ char sZ0[8192];
  __shared__ char sZ1[8192];
  __shared__ char U[33792];      // halo (4x66x64 bf16) -> sW/sH0/sH1 -> sO
  __shared__ float wtab[640];    // [9][64] dw weights + [64] bias

  const int tid = threadIdx.x;
  const int lane = tid & 63, wid = tid >> 6;
  const int bid = blockIdx.x;
  const int b = bid / 1152;
  const int r2 = bid - b * 1152;
  const int hp = r2 / 6, wseg = r2 - (r2 / 6) * 6;
  const int h0 = hp * 2, w0 = wseg * 64;
  const long ibase = (long)b * HW;

  // --- stage dw weights transposed + bias ---
#pragma unroll
  for (int it = 0; it < 3; ++it) {
    int idx = it * 256 + tid;
    if (idx < 576) wtab[idx] = ldw[(idx & 63) * 9 + (idx >> 6)];
    else if (idx < 640) wtab[idx] = ldb[idx - 576];
  }

  // --- load halo: rows h0-1..h0+2, px w0-1..w0+64, bf16, 16B chunks ---
  for (int it = 0; it < 9; ++it) {
    int idx = it * 256 + tid;
    if (idx >= 2112) break;
    int hr = idx / 528;
    int rq = idx - hr * 528;
    int px = rq >> 3, c8 = rq & 7;
    int h = h0 - 1 + hr, w = w0 - 1 + px;
    uint4 v = make_uint4(0, 0, 0, 0);
    if (h >= 0 && h < Hh && w >= 0 && w < Ww) {
      long t = ibase + (long)h * Ww + w;
      v = *(const uint4*)((const char*)yg + t * 128 + c8 * 16);
    }
    *(uint4*)(U + (hr * 66 + px) * 128 + c8 * 16) = v;
  }
  __syncthreads();

  // --- dw 3x3 conv: halo -> sZ[r] (bf16 swizzled) ---
  {
    const int c8 = tid & 7, c0 = c8 * 8;
#pragma unroll
    for (int it = 0; it < 4; ++it) {
      int task = it * 256 + tid;
      int r = task >> 9;
      int px = (task >> 3) & 63;
      float a8[8];
#pragma unroll
      for (int j = 0; j < 8; ++j) a8[j] = wtab[576 + c0 + j];
#pragma unroll
      for (int dy = 0; dy < 3; ++dy)
#pragma unroll
        for (int dx = 0; dx < 3; ++dx) {
          bf16x8 v = *(const bf16x8*)(U + ((r + dy) * 66 + px + dx) * 128 + c8 * 16);
          const float* wk = wtab + (dy * 3 + dx) * 64 + c0;
#pragma unroll
          for (int j = 0; j < 8; ++j) a8[j] += bf2f((unsigned short)v[j]) * wk[j];
        }
      char* sZ = r ? sZ1 : sZ0;
      bf16x8 o;
#pragma unroll
      for (int j = 0; j < 8; ++j) o[j] = (short)f2bf_u(a8[j]);
      *(bf16x8*)(sZ + px * 128 + ((c8 * 16) ^ ((px & 7) << 4))) = o;
    }
  }
  __syncthreads();

  // --- MLP: fc1 + GELU + fc2, both tiles ---
  char* sW  = U;
  char* sH0 = U + 8192;
  char* sH1 = U + 16384;
  const int cbase = lane & 15;
  const int rbase = wid * 16 + (lane >> 4) * 4;
  f32x4 res0[4], res1[4];
#pragma unroll
  for (int nt = 0; nt < 4; ++nt) { res0[nt] = (f32x4){0.f,0.f,0.f,0.f}; res1[nt] = (f32x4){0.f,0.f,0.f,0.f}; }

  for (int jc = 0; jc < 4; ++jc) {
    stage_wtile(sW, f1w + jc * 4096, 64, tid);
    __syncthreads();
#pragma unroll
    for (int t = 0; t < 2; ++t) {
      f32x4 acc[4];
#pragma unroll
      for (int nt = 0; nt < 4; ++nt) acc[nt] = (f32x4){0.f,0.f,0.f,0.f};
      mfma64(t ? sZ1 : sZ0, sW, wid, lane, acc);
      char* sH = t ? sH1 : sH0;
#pragma unroll
      for (int nt = 0; nt < 4; ++nt) {
        const int col = nt * 16 + cbase;
        const float bv = f1b[jc * 64 + col];
#pragma unroll
        for (int reg = 0; reg < 4; ++reg) {
          const int row = rbase + reg;
          *(unsigned short*)(sH + row * 128 + ((col * 2) ^ ((row & 7) << 4))) =
              f2bf_u(gelu_exact(acc[nt][reg] + bv));
        }
      }
    }
    __syncthreads();
    stage_wtile(sW, f2w + jc * 64, 256, tid);
    __syncthreads();
    mfma64(sH0, sW, wid, lane, res0);
    mfma64(sH1, sW, wid, lane, res1);
    __syncthreads();
  }

  // --- epilogue per tile: + f2b + x1 -> sO -> transposed BCHW store ---
  float* sO = (float*)U;
#pragma unroll
  for (int t = 0; t < 2; ++t) {
    const f32x4* res = t ? res1 : res0;
    const long p0t = ibase + (long)(h0 + t) * Ww + w0;
#pragma unroll
    for (int nt = 0; nt < 4; ++nt) {
      const int col = nt * 16 + cbase;
      const float bv = f2b[col];
#pragma unroll
      for (int reg = 0; reg < 4; ++reg) {
        const int row = rbase + reg;
        sO[row * 65 + col] = res[nt][reg] + bv + x1g[(p0t + row) * 64 + col];
      }
    }
    __syncthreads();
#pragma unroll
    for (int it = 0; it < 16; ++it) {
      int c = it * 4 + (tid >> 6);
      int wo = tid & 63;
      out[(((long)(b * Cc + c)) * Hh + (h0 + t)) * Ww + w0 + wo] = sO[wo * 65 + c];
    }
    __syncthreads();
  }
}

// ---------------- launch ----------------

extern "C" void kernel_launch(void* const* d_in, const int* in_sizes, int n_in,
                              void* d_out, int out_size, void* d_ws, size_t ws_size,
                              hipStream_t stream) {
  const float* x    = (const float*)d_in[0];
  const float* n1w  = (const float*)d_in[1];
  const float* n1b  = (const float*)d_in[2];
  const float* qkvw = (const float*)d_in[3];
  const float* qkvb = (const float*)d_in[4];
  const float* posb = (const float*)d_in[5];
  const float* outw = (const float*)d_in[6];
  const float* outb = (const float*)d_in[7];
  const float* cpw  = (const float*)d_in[8];
  const float* cpb  = (const float*)d_in[9];
  const float* pw1w = (const float*)d_in[10];
  const float* pw1b = (const float*)d_in[11];
  const float* dw1w = (const float*)d_in[12];
  const float* dw1b = (const float*)d_in[13];
  const float* tokw = (const float*)d_in[14];
  const float* tokb = (const float*)d_in[15];
  const float* n2w  = (const float*)d_in[16];
  const float* n2b  = (const float*)d_in[17];
  const float* lpw  = (const float*)d_in[18];
  const float* ldw  = (const float*)d_in[19];
  const float* ldb  = (const float*)d_in[20];
  const float* f1w  = (const float*)d_in[21];
  const float* f1b  = (const float*)d_in[22];
  const float* f2w  = (const float*)d_in[23];
  const float* f2b  = (const float*)d_in[24];
  float* out = (float*)d_out;

  float* x1 = (float*)d_ws;                              // f32 [Tt][64]
  unsigned short* y = (unsigned short*)((float*)d_ws + (size_t)Tt * 64);  // bf16 [Tt][64]

  kA<<<dim3(4608), dim3(256), 0, stream>>>(x, x1, y, n1w, n1b, qkvw, qkvb, posb,
                                           outw, outb, cpw, cpb, pw1w, pw1b,
                                           dw1w, dw1b, tokw, tokb, n2w, n2b, lpw);
  kB<<<dim3(2304), dim3(256), 0, stream>>>(y, x1, out, ldw, ldb, f1w, f1b, f2w, f2b);
}

// Round 4
// 211.100 us; speedup vs baseline: 11.5756x; 1.2487x over previous
//
#include <hip/hip_runtime.h>
#include <math.h>

#define Bn 2
#define Cc 64
#define Hh 384
#define Ww 384
#define HW (Hh*Ww)          // 147456
#define Tt (Bn*HW)          // 294912 tokens

using f32x4  = __attribute__((ext_vector_type(4))) float;
using bf16x8 = __attribute__((ext_vector_type(8))) short;

// ---------------- helpers ----------------

__device__ __forceinline__ unsigned short f2bf_u(float f) {
  union { float f; unsigned u; } v; v.f = f;
  return (unsigned short)((v.u + 0x7FFFu + ((v.u >> 16) & 1u)) >> 16);
}
__device__ __forceinline__ float bf2f(unsigned short u) {
  union { unsigned u; float f; } v; v.u = ((unsigned)u) << 16;
  return v.f;
}
__device__ __forceinline__ float gelu_exact(float v) {
  return 0.5f * v * (1.0f + erff(v * 0.70710678118654752f));
}

// stage a 64x64 f32 tile (row stride rs) -> LDS bf16 [64][64], XOR-swizzled (kB only)
__device__ __forceinline__ void stage_wtile(char* dst, const float* __restrict__ g, int rs, int tid) {
#pragma unroll
  for (int half = 0; half < 2; ++half) {
    int q = tid + half * 256;
    int row = q >> 3, ks = q & 7;
    const float* gp = g + (long)row * rs + ks * 8;
    float4 a = *(const float4*)gp;
    float4 b = *(const float4*)(gp + 4);
    bf16x8 o;
    o[0] = (short)f2bf_u(a.x); o[1] = (short)f2bf_u(a.y);
    o[2] = (short)f2bf_u(a.z); o[3] = (short)f2bf_u(a.w);
    o[4] = (short)f2bf_u(b.x); o[5] = (short)f2bf_u(b.y);
    o[6] = (short)f2bf_u(b.z); o[7] = (short)f2bf_u(b.w);
    *(bf16x8*)(dst + row * 128 + ((ks * 16) ^ ((row & 7) << 4))) = o;
  }
}

// 64-row GEMM (kB): out rows 16*wid.., acc accumulates
__device__ __forceinline__ void mfma64(const char* sA, const char* sB, int wid, int lane, f32x4 acc[4]) {
  const int r = lane & 15, kq = lane >> 4;
#pragma unroll
  for (int kh = 0; kh < 2; ++kh) {
    const int arow = wid * 16 + r;
    bf16x8 af = *(const bf16x8*)(sA + arow * 128 + ((kh * 64 + kq * 16) ^ ((arow & 7) << 4)));
#pragma unroll
    for (int nt = 0; nt < 4; ++nt) {
      const int brow = nt * 16 + r;
      bf16x8 bfv = *(const bf16x8*)(sB + brow * 128 + ((kh * 64 + kq * 16) ^ ((brow & 7) << 4)));
      acc[nt] = __builtin_amdgcn_mfma_f32_16x16x32_bf16(af, bfv, acc[nt], 0, 0, 0);
    }
  }
}

// ================= K_A v2: 128-token (2-window) fused block =================
// LN1 + REMSA + residual + LN2 + LeFF-pw. Reads x (BCHW); writes x1 (f32 [t][c]), y (bf16 [t][c]).

__global__ __launch_bounds__(256, 2) void kA(
    const float* __restrict__ x, float* __restrict__ x1g, unsigned short* __restrict__ yg,
    const float* __restrict__ n1w, const float* __restrict__ n1b,
    const float* __restrict__ qkvw, const float* __restrict__ qkvb,
    const float* __restrict__ posb,
    const float* __restrict__ outw, const float* __restrict__ outb,
    const float* __restrict__ cpw, const float* __restrict__ cpb,
    const float* __restrict__ pw1w, const float* __restrict__ pw1b,
    const float* __restrict__ dw1w, const float* __restrict__ dw1b,
    const float* __restrict__ tokw, const float* __restrict__ tokb,
    const float* __restrict__ n2w, const float* __restrict__ n2b,
    const float* __restrict__ lpw) {
  __shared__ char sX[16384];   // 128 rows x 128B, bf16 swizzled (LN1'd x -> ao -> LN2'd x1)
  __shared__ char sW[8192];    // 64x64 weight tile bf16 swizzled
  __shared__ char sQ[49152];   // 3 x 16KB tiles (conv-branch scratch, then qkv; stats alias; y staging)

  const int tid = threadIdx.x;
  const int lane = tid & 63, wid = tid >> 6;
  const int blk = blockIdx.x;
  const int b = blk / 1152;
  const int rr = blk - b * 1152;
  const int wy = rr / 24, wxp = rr - (rr / 24) * 24;
  const int h0 = wy * 8, w0 = wxp * 16;
  const long ibase = (long)b * HW;

  // ---- weight prefetch machinery: 16 f32 regs per thread ----
  float4 wr0, wr1, wr2, wr3;
  const int wrow = tid >> 2, wc0 = (tid & 3) * 16;
  auto WLOAD = [&](const float* g) {
    const float* p = g + (long)wrow * 64 + wc0;
    wr0 = *(const float4*)p;      wr1 = *(const float4*)(p + 4);
    wr2 = *(const float4*)(p + 8); wr3 = *(const float4*)(p + 12);
  };
  auto WSTORE = [&]() {
    const int sw = (wrow & 7) << 4;
    bf16x8 o1, o2;
    o1[0]=(short)f2bf_u(wr0.x); o1[1]=(short)f2bf_u(wr0.y); o1[2]=(short)f2bf_u(wr0.z); o1[3]=(short)f2bf_u(wr0.w);
    o1[4]=(short)f2bf_u(wr1.x); o1[5]=(short)f2bf_u(wr1.y); o1[6]=(short)f2bf_u(wr1.z); o1[7]=(short)f2bf_u(wr1.w);
    o2[0]=(short)f2bf_u(wr2.x); o2[1]=(short)f2bf_u(wr2.y); o2[2]=(short)f2bf_u(wr2.z); o2[3]=(short)f2bf_u(wr2.w);
    o2[4]=(short)f2bf_u(wr3.x); o2[5]=(short)f2bf_u(wr3.y); o2[6]=(short)f2bf_u(wr3.z); o2[7]=(short)f2bf_u(wr3.w);
    *(bf16x8*)(sW + wrow * 128 + ((2 * wc0) ^ sw)) = o1;
    *(bf16x8*)(sW + wrow * 128 + ((2 * wc0 + 16) ^ sw)) = o2;
  };

  // ---- gather x (coalesced 64B lines) + LN1 partial stats in registers ----
  WLOAD(cpw);
  const int iyh = wid & 1, cpar = wid >> 1;
  const int iy = iyh * 4 + (lane >> 4);
  const int ix = lane & 15;
  const int rtok = iy * 16 + ix;
  const float* xb = x + (long)(b * 64) * HW + (long)(h0 + iy) * Ww + (w0 + ix);
  float vx[32]; float s0 = 0.f, s1 = 0.f;
#pragma unroll
  for (int k = 0; k < 32; ++k) {
    float v = xb[(long)(2 * k + cpar) * HW];
    vx[k] = v; s0 += v; s1 += v * v;
  }
  float* psA = (float*)sQ;      // [2][128] sums
  float* psB = psA + 256;       // [2][128] sumsq
  float* smu = psA + 512;       // [128]
  float* srs = psA + 640;       // [128]
  psA[cpar * 128 + rtok] = s0;
  psB[cpar * 128 + rtok] = s1;
  WSTORE();                     // cpw -> sW (sW not yet read)
  WLOAD(pw1w);
  __syncthreads();
  if (tid < 128) {
    float s = psA[tid] + psA[128 + tid];
    float q = psB[tid] + psB[128 + tid];
    float m = s * (1.f / 64.f);
    float var = q * (1.f / 64.f) - m * m;
    smu[tid] = m; srs[tid] = rsqrtf(var + 1e-5f);
  }
  __syncthreads();
  {
    float m = smu[rtok], ri = srs[rtok];
    const int swz = (rtok & 7) << 4;
#pragma unroll
    for (int k = 0; k < 32; ++k) {
      int c = 2 * k + cpar;
      float nv = (vx[k] - m) * ri * n1w[c] + n1b[c];
      *(unsigned short*)(sX + rtok * 128 + ((2 * c) ^ swz)) = f2bf_u(nv);
    }
  }
  __syncthreads();   // sX (LN1) + sW (cpw) ready

  // ---- GEMM machinery (M=128: 2 m-tiles/wave) ----
  const int fr = lane & 15, kq = lane >> 4;
  f32x4 acc[2][4], res[2][4];
  auto ZERO = [&](f32x4 a[2][4]) {
#pragma unroll
    for (int m = 0; m < 2; ++m)
#pragma unroll
      for (int nt = 0; nt < 4; ++nt) a[m][nt] = (f32x4){0.f, 0.f, 0.f, 0.f};
  };
  auto GEMM = [&](const char* A, f32x4 a[2][4]) {
#pragma unroll
    for (int kh = 0; kh < 2; ++kh) {
#pragma unroll
      for (int m = 0; m < 2; ++m) {
        int arow = wid * 32 + m * 16 + fr;
        bf16x8 af = *(const bf16x8*)(A + arow * 128 + ((kh * 64 + kq * 16) ^ ((arow & 7) << 4)));
#pragma unroll
        for (int nt = 0; nt < 4; ++nt) {
          int brow = nt * 16 + fr;
          bf16x8 bv = *(const bf16x8*)(sW + brow * 128 + ((kh * 64 + kq * 16) ^ ((brow & 7) << 4)));
          a[m][nt] = __builtin_amdgcn_mfma_f32_16x16x32_bf16(af, bv, a[m][nt], 0, 0, 0);
        }
      }
    }
  };
  auto EPI = [&](char* dst, f32x4 a[2][4], const float* bias) {
#pragma unroll
    for (int m = 0; m < 2; ++m) {
      int rb = wid * 32 + m * 16 + kq * 4;
#pragma unroll
      for (int nt = 0; nt < 4; ++nt) {
        int col = nt * 16 + fr;
        float bvv = bias[col];
#pragma unroll
        for (int reg = 0; reg < 4; ++reg) {
          int row = rb + reg;
          *(unsigned short*)(dst + row * 128 + ((2 * col) ^ ((row & 7) << 4))) =
              f2bf_u(a[m][nt][reg] + bvv);
        }
      }
    }
  };

  // --- GEMM1 convp: sX -> sQ0 ---
  ZERO(acc); GEMM(sX, acc); EPI(sQ, acc, cpb);
  __syncthreads();
  WSTORE(); WLOAD(tokw);          // pw1w -> sW
  __syncthreads();
  // --- GEMM2 pw1: sQ0 -> sQ1 ---
  ZERO(acc); GEMM(sQ, acc); EPI(sQ + 16384, acc, pw1b);
  __syncthreads();
  // --- dw1 depthwise over window sequence s: sQ1 -> sQ0 ; stage tokw ---
  {
    const int c = tid & 63, tq = tid >> 6;
    float wv0 = dw1w[c * 3], wv1 = dw1w[c * 3 + 1], wv2 = dw1w[c * 3 + 2], bia = dw1b[c];
    const char* src = sQ + 16384;
#pragma unroll
    for (int wl = 0; wl < 2; ++wl) {
#pragma unroll
      for (int k = 0; k < 16; ++k) {
        int s = tq * 16 + k;
        int r0 = ((s >> 3) << 4) + wl * 8 + (s & 7);
        float v = bia + bf2f(*(const unsigned short*)(src + r0 * 128 + ((2 * c) ^ ((r0 & 7) << 4)))) * wv1;
        if (s > 0) {
          int rm = (((s - 1) >> 3) << 4) + wl * 8 + ((s - 1) & 7);
          v += bf2f(*(const unsigned short*)(src + rm * 128 + ((2 * c) ^ ((rm & 7) << 4)))) * wv0;
        }
        if (s < 63) {
          int rp = (((s + 1) >> 3) << 4) + wl * 8 + ((s + 1) & 7);
          v += bf2f(*(const unsigned short*)(src + rp * 128 + ((2 * c) ^ ((rp & 7) << 4)))) * wv2;
        }
        *(unsigned short*)(sQ + r0 * 128 + ((2 * c) ^ ((r0 & 7) << 4))) = f2bf_u(v);
      }
    }
  }
  WSTORE(); WLOAD(qkvw);          // tokw -> sW
  __syncthreads();
  // --- GEMM3 tok: sQ0 -> res ---
  ZERO(res); GEMM(sQ, res);
  __syncthreads();
  WSTORE(); WLOAD(qkvw + 4096);   // qkv g0 -> sW
  __syncthreads();
  ZERO(acc); GEMM(sX, acc); EPI(sQ, acc, qkvb);
  __syncthreads();
  WSTORE(); WLOAD(qkvw + 8192);   // qkv g1 -> sW
  __syncthreads();
  ZERO(acc); GEMM(sX, acc); EPI(sQ + 16384, acc, qkvb + 64);
  __syncthreads();
  WSTORE(); WLOAD(outw);          // qkv g2 -> sW
  __syncthreads();
  ZERO(acc); GEMM(sX, acc); EPI(sQ + 32768, acc, qkvb + 128);
  __syncthreads();
  WSTORE(); WLOAD(lpw);           // outw -> sW

  // --- per-token 4x4 head-axis attention: sQ tiles -> sX (ao) ---
  {
    const int r = tid & 127;
    const int hb = (tid >> 7) << 1;           // heads {hb, hb+1}
    const int s = ((r >> 4) << 3) + (r & 7);  // window-local token index
    const int swz = (r & 7) << 4;
    auto LD16 = [&](int gcol, float* o) {
      const char* base = sQ + ((gcol >> 6) * 16384) + r * 128;
      int c0 = (gcol & 63) * 2;
      bf16x8 u = *(const bf16x8*)(base + (c0 ^ swz));
      bf16x8 w2_ = *(const bf16x8*)(base + ((c0 + 16) ^ swz));
#pragma unroll
      for (int j = 0; j < 8; ++j) {
        o[j] = bf2f((unsigned short)u[j]); o[8 + j] = bf2f((unsigned short)w2_[j]);
      }
    };
    float q0[16], q1[16];
    LD16(48 * hb, q0);
    LD16(48 * hb + 48, q1);
    float sc0[4], sc1[4];
#pragma unroll
    for (int g = 0; g < 4; ++g) {
      float kk[16]; LD16(48 * g + 16, kk);
      float a0 = 0.f, a1 = 0.f;
#pragma unroll
      for (int d = 0; d < 16; ++d) { a0 += q0[d] * kk[d]; a1 += q1[d] * kk[d]; }
      sc0[g] = a0 * 0.25f + posb[s * 16 + hb * 4 + g];
      sc1[g] = a1 * 0.25f + posb[s * 16 + hb * 4 + 4 + g];
    }
    float m0 = fmaxf(fmaxf(sc0[0], sc0[1]), fmaxf(sc0[2], sc0[3]));
    float m1 = fmaxf(fmaxf(sc1[0], sc1[1]), fmaxf(sc1[2], sc1[3]));
    float e0[4], e1[4]; float t0 = 0.f, t1 = 0.f;
#pragma unroll
    for (int g = 0; g < 4; ++g) {
      e0[g] = expf(sc0[g] - m0); t0 += e0[g];
      e1[g] = expf(sc1[g] - m1); t1 += e1[g];
    }
    float i0 = 1.f / t0, i1 = 1.f / t1;
    float ao0[16], ao1[16];
#pragma unroll
    for (int d = 0; d < 16; ++d) { ao0[d] = 0.f; ao1[d] = 0.f; }
#pragma unroll
    for (int g = 0; g < 4; ++g) {
      float vv[16]; LD16(48 * g + 32, vv);
#pragma unroll
      for (int d = 0; d < 16; ++d) { ao0[d] += e0[g] * vv[d]; ao1[d] += e1[g] * vv[d]; }
    }
    bf16x8 o1, o2;
#pragma unroll
    for (int j = 0; j < 8; ++j) { o1[j] = (short)f2bf_u(ao0[j] * i0); o2[j] = (short)f2bf_u(ao0[8 + j] * i0); }
    *(bf16x8*)(sX + r * 128 + ((hb * 32) ^ swz)) = o1;
    *(bf16x8*)(sX + r * 128 + ((hb * 32 + 16) ^ swz)) = o2;
#pragma unroll
    for (int j = 0; j < 8; ++j) { o1[j] = (short)f2bf_u(ao1[j] * i1); o2[j] = (short)f2bf_u(ao1[8 + j] * i1); }
    *(bf16x8*)(sX + r * 128 + ((hb * 32 + 32) ^ swz)) = o1;
    *(bf16x8*)(sX + r * 128 + ((hb * 32 + 48) ^ swz)) = o2;
  }
  __syncthreads();
  // --- GEMM7 out-proj: sX(ao) -> res accumulate ---
  GEMM(sX, res);
  __syncthreads();
  WSTORE();   // lpw -> sW

  // --- epilogue: x1 = x + remsa (re-read x, frag layout); write x1; LN2 via shfl -> sX ---
  {
    float ob[4], n2wv[4], n2bv[4];
#pragma unroll
    for (int nt = 0; nt < 4; ++nt) {
      int col = nt * 16 + fr;
      ob[nt] = outb[col] + tokb[col];
      n2wv[nt] = n2w[col]; n2bv[nt] = n2b[col];
    }
#pragma unroll
    for (int m = 0; m < 2; ++m) {
#pragma unroll
      for (int reg = 0; reg < 4; ++reg) {
        int row = wid * 32 + m * 16 + kq * 4 + reg;
        int hh = h0 + (row >> 4), wwp = w0 + (row & 15);
        long t = ibase + (long)hh * Ww + wwp;
        float vals[4]; float sv = 0.f, sq = 0.f;
#pragma unroll
        for (int nt = 0; nt < 4; ++nt) {
          int col = nt * 16 + fr;
          float xv = x[((long)(b * 64 + col)) * HW + (long)hh * Ww + wwp];
          float v = res[m][nt][reg] + ob[nt] + xv;
          x1g[t * 64 + col] = v;
          vals[nt] = v; sv += v; sq += v * v;
        }
#pragma unroll
        for (int msk = 1; msk <= 8; msk <<= 1) {
          sv += __shfl_xor(sv, msk, 64);
          sq += __shfl_xor(sq, msk, 64);
        }
        float mmu = sv * (1.f / 64.f);
        float ri = rsqrtf(sq * (1.f / 64.f) - mmu * mmu + 1e-5f);
        const int swz = (row & 7) << 4;
#pragma unroll
        for (int nt = 0; nt < 4; ++nt) {
          int col = nt * 16 + fr;
          *(unsigned short*)(sX + row * 128 + ((2 * col) ^ swz)) =
              f2bf_u((vals[nt] - mmu) * ri * n2wv[nt] + n2bv[nt]);
        }
      }
    }
  }
  __syncthreads();
  // --- GEMM8 LeFF-pw (no bias): sX -> flat bf16 stage in sQ -> y ---
  ZERO(acc); GEMM(sX, acc);
  {
    unsigned short* st = (unsigned short*)sQ;
#pragma unroll
    for (int m = 0; m < 2; ++m) {
      int rb = wid * 32 + m * 16 + kq * 4;
#pragma unroll
      for (int nt = 0; nt < 4; ++nt) {
        int col = nt * 16 + fr;
#pragma unroll
        for (int reg = 0; reg < 4; ++reg)
          st[(rb + reg) * 64 + col] = f2bf_u(acc[m][nt][reg]);
      }
    }
  }
  __syncthreads();
#pragma unroll
  for (int it = 0; it < 4; ++it) {
    int idx = it * 256 + tid;
    int tr = idx >> 3, c8 = idx & 7;
    long t = ibase + (long)(h0 + (tr >> 4)) * Ww + (w0 + (tr & 15));
    *(uint4*)((char*)yg + t * 128 + c8 * 16) = *(const uint4*)((const char*)sQ + idx * 16);
  }
}

// ================= K_B: 3x3 depthwise + fc1+GELU+fc2 + residual + BCHW store =================

__global__ __launch_bounds__(256, 3) void kB(
    const unsigned short* __restrict__ yg, const float* __restrict__ x1g,
    float* __restrict__ out,
    const float* __restrict__ ldw, const float* __restrict__ ldb,
    const float* __restrict__ f1w, const float* __restrict__ f1b,
    const float* __restrict__ f2w, const float* __restrict__ f2b) {
  __shared__ char sZ0[8192];
  __shared__ char sZ1[8192];
  __shared__ char U[33792];      // halo (4x66x64 bf16) -> sW/sH0/sH1 -> sO
  __shared__ float wtab[640];    // [9][64] dw weights + [64] bias

  const int tid = threadIdx.x;
  const int lane = tid & 63, wid = tid >> 6;
  const int bid = blockIdx.x;
  const int b = bid / 1152;
  const int r2 = bid - b * 1152;
  const int hp = r2 / 6, wseg = r2 - (r2 / 6) * 6;
  const int h0 = hp * 2, w0 = wseg * 64;
  const long ibase = (long)b * HW;

#pragma unroll
  for (int it = 0; it < 3; ++it) {
    int idx = it * 256 + tid;
    if (idx < 576) wtab[idx] = ldw[(idx & 63) * 9 + (idx >> 6)];
    else if (idx < 640) wtab[idx] = ldb[idx - 576];
  }

  for (int it = 0; it < 9; ++it) {
    int idx = it * 256 + tid;
    if (idx >= 2112) break;
    int hr = idx / 528;
    int rq = idx - hr * 528;
    int px = rq >> 3, c8 = rq & 7;
    int h = h0 - 1 + hr, w = w0 - 1 + px;
    uint4 v = make_uint4(0, 0, 0, 0);
    if (h >= 0 && h < Hh && w >= 0 && w < Ww) {
      long t = ibase + (long)h * Ww + w;
      v = *(const uint4*)((const char*)yg + t * 128 + c8 * 16);
    }
    *(uint4*)(U + (hr * 66 + px) * 128 + c8 * 16) = v;
  }
  __syncthreads();

  {
    const int c8 = tid & 7, c0 = c8 * 8;
#pragma unroll
    for (int it = 0; it < 4; ++it) {
      int task = it * 256 + tid;
      int r = task >> 9;
      int px = (task >> 3) & 63;
      float a8[8];
#pragma unroll
      for (int j = 0; j < 8; ++j) a8[j] = wtab[576 + c0 + j];
#pragma unroll
      for (int dy = 0; dy < 3; ++dy)
#pragma unroll
        for (int dx = 0; dx < 3; ++dx) {
          bf16x8 v = *(const bf16x8*)(U + ((r + dy) * 66 + px + dx) * 128 + c8 * 16);
          const float* wk = wtab + (dy * 3 + dx) * 64 + c0;
#pragma unroll
          for (int j = 0; j < 8; ++j) a8[j] += bf2f((unsigned short)v[j]) * wk[j];
        }
      char* sZ = r ? sZ1 : sZ0;
      bf16x8 o;
#pragma unroll
      for (int j = 0; j < 8; ++j) o[j] = (short)f2bf_u(a8[j]);
      *(bf16x8*)(sZ + px * 128 + ((c8 * 16) ^ ((px & 7) << 4))) = o;
    }
  }
  __syncthreads();

  char* sW  = U;
  char* sH0 = U + 8192;
  char* sH1 = U + 16384;
  const int cbase = lane & 15;
  const int rbase = wid * 16 + (lane >> 4) * 4;
  f32x4 res0[4], res1[4];
#pragma unroll
  for (int nt = 0; nt < 4; ++nt) { res0[nt] = (f32x4){0.f,0.f,0.f,0.f}; res1[nt] = (f32x4){0.f,0.f,0.f,0.f}; }

  for (int jc = 0; jc < 4; ++jc) {
    stage_wtile(sW, f1w + jc * 4096, 64, tid);
    __syncthreads();
#pragma unroll
    for (int t = 0; t < 2; ++t) {
      f32x4 acc[4];
#pragma unroll
      for (int nt = 0; nt < 4; ++nt) acc[nt] = (f32x4){0.f,0.f,0.f,0.f};
      mfma64(t ? sZ1 : sZ0, sW, wid, lane, acc);
      char* sH = t ? sH1 : sH0;
#pragma unroll
      for (int nt = 0; nt < 4; ++nt) {
        const int col = nt * 16 + cbase;
        const float bv = f1b[jc * 64 + col];
#pragma unroll
        for (int reg = 0; reg < 4; ++reg) {
          const int row = rbase + reg;
          *(unsigned short*)(sH + row * 128 + ((col * 2) ^ ((row & 7) << 4))) =
              f2bf_u(gelu_exact(acc[nt][reg] + bv));
        }
      }
    }
    __syncthreads();
    stage_wtile(sW, f2w + jc * 64, 256, tid);
    __syncthreads();
    mfma64(sH0, sW, wid, lane, res0);
    mfma64(sH1, sW, wid, lane, res1);
    __syncthreads();
  }

  float* sO = (float*)U;
#pragma unroll
  for (int t = 0; t < 2; ++t) {
    const f32x4* res = t ? res1 : res0;
    const long p0t = ibase + (long)(h0 + t) * Ww + w0;
#pragma unroll
    for (int nt = 0; nt < 4; ++nt) {
      const int col = nt * 16 + cbase;
      const float bv = f2b[col];
#pragma unroll
      for (int reg = 0; reg < 4; ++reg) {
        const int row = rbase + reg;
        sO[row * 65 + col] = res[nt][reg] + bv + x1g[(p0t + row) * 64 + col];
      }
    }
    __syncthreads();
#pragma unroll
    for (int it = 0; it < 16; ++it) {
      int c = it * 4 + (tid >> 6);
      int wo = tid & 63;
      out[(((long)(b * Cc + c)) * Hh + (h0 + t)) * Ww + w0 + wo] = sO[wo * 65 + c];
    }
    __syncthreads();
  }
}

// ---------------- launch ----------------

extern "C" void kernel_launch(void* const* d_in, const int* in_sizes, int n_in,
                              void* d_out, int out_size, void* d_ws, size_t ws_size,
                              hipStream_t stream) {
  const float* x    = (const float*)d_in[0];
  const float* n1w  = (const float*)d_in[1];
  const float* n1b  = (const float*)d_in[2];
  const float* qkvw = (const float*)d_in[3];
  const float* qkvb = (const float*)d_in[4];
  const float* posb = (const float*)d_in[5];
  const float* outw = (const float*)d_in[6];
  const float* outb = (const float*)d_in[7];
  const float* cpw  = (const float*)d_in[8];
  const float* cpb  = (const float*)d_in[9];
  const float* pw1w = (const float*)d_in[10];
  const float* pw1b = (const float*)d_in[11];
  const float* dw1w = (const float*)d_in[12];
  const float* dw1b = (const float*)d_in[13];
  const float* tokw = (const float*)d_in[14];
  const float* tokb = (const float*)d_in[15];
  const float* n2w  = (const float*)d_in[16];
  const float* n2b  = (const float*)d_in[17];
  const float* lpw  = (const float*)d_in[18];
  const float* ldw  = (const float*)d_in[19];
  const float* ldb  = (const float*)d_in[20];
  const float* f1w  = (const float*)d_in[21];
  const float* f1b  = (const float*)d_in[22];
  const float* f2w  = (const float*)d_in[23];
  const float* f2b  = (const float*)d_in[24];
  float* out = (float*)d_out;

  float* x1 = (float*)d_ws;                                              // f32 [Tt][64]
  unsigned short* y = (unsigned short*)((float*)d_ws + (size_t)Tt * 64); // bf16 [Tt][64]

  kA<<<dim3(2304), dim3(256), 0, stream>>>(x, x1, y, n1w, n1b, qkvw, qkvb, posb,
                                           outw, outb, cpw, cpb, pw1w, pw1b,
                                           dw1w, dw1b, tokw, tokb, n2w, n2b, lpw);
  kB<<<dim3(2304), dim3(256), 0, stream>>>(y, x1, out, ldw, ldb, f1w, f1b, f2w, f2b);
}

// Round 5
// 203.167 us; speedup vs baseline: 12.0276x; 1.0390x over previous
//
#include <hip/hip_runtime.h>
#include <hip/hip_bf16.h>
#include <math.h>

#define Bn 2
#define Cc 64
#define Hh 384
#define Ww 384
#define HW (Hh*Ww)          // 147456
#define Tt (Bn*HW)          // 294912 tokens

using f32x4  = __attribute__((ext_vector_type(4))) float;
using bf16x8 = __attribute__((ext_vector_type(8))) short;

// ---------------- helpers ----------------

__device__ __forceinline__ unsigned short f2bf_u(float f) {
  // plain cast -> compiler emits v_cvt_pk_bf16_f32 pairs (guide m240)
  return __builtin_bit_cast(unsigned short, __float2bfloat16(f));
}
__device__ __forceinline__ float bf2f(unsigned short u) {
  union { unsigned u; float f; } v; v.u = ((unsigned)u) << 16;
  return v.f;
}
__device__ __forceinline__ float gelu_exact(float v) {
  return 0.5f * v * (1.0f + erff(v * 0.70710678118654752f));
}

// stage a 64x64 f32 tile (row stride rs) -> LDS bf16 [64][64], XOR-swizzled (kB only)
__device__ __forceinline__ void stage_wtile(char* dst, const float* __restrict__ g, int rs, int tid) {
#pragma unroll
  for (int half = 0; half < 2; ++half) {
    int q = tid + half * 256;
    int row = q >> 3, ks = q & 7;
    const float* gp = g + (long)row * rs + ks * 8;
    float4 a = *(const float4*)gp;
    float4 b = *(const float4*)(gp + 4);
    bf16x8 o;
    o[0] = (short)f2bf_u(a.x); o[1] = (short)f2bf_u(a.y);
    o[2] = (short)f2bf_u(a.z); o[3] = (short)f2bf_u(a.w);
    o[4] = (short)f2bf_u(b.x); o[5] = (short)f2bf_u(b.y);
    o[6] = (short)f2bf_u(b.z); o[7] = (short)f2bf_u(b.w);
    *(bf16x8*)(dst + row * 128 + ((ks * 16) ^ ((row & 7) << 4))) = o;
  }
}

// 64-row GEMM (kB): out rows 16*wid.., acc accumulates
__device__ __forceinline__ void mfma64(const char* sA, const char* sB, int wid, int lane, f32x4 acc[4]) {
  const int r = lane & 15, kq = lane >> 4;
#pragma unroll
  for (int kh = 0; kh < 2; ++kh) {
    const int arow = wid * 16 + r;
    bf16x8 af = *(const bf16x8*)(sA + arow * 128 + ((kh * 64 + kq * 16) ^ ((arow & 7) << 4)));
#pragma unroll
    for (int nt = 0; nt < 4; ++nt) {
      const int brow = nt * 16 + r;
      bf16x8 bfv = *(const bf16x8*)(sB + brow * 128 + ((kh * 64 + kq * 16) ^ ((brow & 7) << 4)));
      acc[nt] = __builtin_amdgcn_mfma_f32_16x16x32_bf16(af, bfv, acc[nt], 0, 0, 0);
    }
  }
}

// ================= K_A: 128-token (2-window) fused block =================
// LN1 + REMSA + residual + LN2 + LeFF-pw. Reads x (BCHW); writes x1 (bf16 [t][c]), y (bf16 [t][c]).

__global__ __launch_bounds__(256, 2) void kA(
    const float* __restrict__ x, unsigned short* __restrict__ x1g, unsigned short* __restrict__ yg,
    const float* __restrict__ n1w, const float* __restrict__ n1b,
    const float* __restrict__ qkvw, const float* __restrict__ qkvb,
    const float* __restrict__ posb,
    const float* __restrict__ outw, const float* __restrict__ outb,
    const float* __restrict__ cpw, const float* __restrict__ cpb,
    const float* __restrict__ pw1w, const float* __restrict__ pw1b,
    const float* __restrict__ dw1w, const float* __restrict__ dw1b,
    const float* __restrict__ tokw, const float* __restrict__ tokb,
    const float* __restrict__ n2w, const float* __restrict__ n2b,
    const float* __restrict__ lpw) {
  __shared__ char sX[16384];   // 128 rows x 128B, bf16 swizzled
  __shared__ char sW[8192];    // 64x64 weight tile bf16 swizzled
  __shared__ char sQ[49152];   // conv scratch / qkv tiles / f32 handoff tile + stats

  const int tid = threadIdx.x;
  const int lane = tid & 63, wid = tid >> 6;
  const int blk = blockIdx.x;
  const int b = blk / 1152;
  const int rr = blk - b * 1152;
  const int wy = rr / 24, wxp = rr - (rr / 24) * 24;
  const int h0 = wy * 8, w0 = wxp * 16;
  const long ibase = (long)b * HW;

  // ---- weight prefetch machinery ----
  float4 wr0, wr1, wr2, wr3;
  const int wrow = tid >> 2, wc0 = (tid & 3) * 16;
  auto WLOAD = [&](const float* g) {
    const float* p = g + (long)wrow * 64 + wc0;
    wr0 = *(const float4*)p;      wr1 = *(const float4*)(p + 4);
    wr2 = *(const float4*)(p + 8); wr3 = *(const float4*)(p + 12);
  };
  auto WSTORE = [&]() {
    const int sw = (wrow & 7) << 4;
    bf16x8 o1, o2;
    o1[0]=(short)f2bf_u(wr0.x); o1[1]=(short)f2bf_u(wr0.y); o1[2]=(short)f2bf_u(wr0.z); o1[3]=(short)f2bf_u(wr0.w);
    o1[4]=(short)f2bf_u(wr1.x); o1[5]=(short)f2bf_u(wr1.y); o1[6]=(short)f2bf_u(wr1.z); o1[7]=(short)f2bf_u(wr1.w);
    o2[0]=(short)f2bf_u(wr2.x); o2[1]=(short)f2bf_u(wr2.y); o2[2]=(short)f2bf_u(wr2.z); o2[3]=(short)f2bf_u(wr2.w);
    o2[4]=(short)f2bf_u(wr3.x); o2[5]=(short)f2bf_u(wr3.y); o2[6]=(short)f2bf_u(wr3.z); o2[7]=(short)f2bf_u(wr3.w);
    *(bf16x8*)(sW + wrow * 128 + ((2 * wc0) ^ sw)) = o1;
    *(bf16x8*)(sW + wrow * 128 + ((2 * wc0 + 16) ^ sw)) = o2;
  };

  // ---- gather x + LN1 partials; each thread owns token rtok, channels c0own..+32 ----
  WLOAD(cpw);
  const int iy = (wid & 1) * 4 + (lane >> 4);
  const int ix = lane & 15;
  const int rtok = iy * 16 + ix;
  const int cpar = wid >> 1;
  const int c0own = cpar * 32;
  const float* xb = x + ((long)(b * 64 + c0own)) * HW + (long)(h0 + iy) * Ww + (w0 + ix);
  float vx[32]; float s0 = 0.f, s1 = 0.f;
#pragma unroll
  for (int k = 0; k < 32; ++k) {
    float v = xb[(long)k * HW];
    vx[k] = v; s0 += v; s1 += v * v;
  }
  float* sQf = (float*)sQ;      // f32 handoff tile [128][67]
  float* psA = sQf + 8576;      // [2][128]
  float* psB = psA + 256;
  float* smu = psA + 512;       // [128]
  float* srs = psA + 640;
  psA[cpar * 128 + rtok] = s0;
  psB[cpar * 128 + rtok] = s1;
  WSTORE(); WLOAD(pw1w);
  __syncthreads();
  if (tid < 128) {
    float s = psA[tid] + psA[128 + tid];
    float q = psB[tid] + psB[128 + tid];
    float m = s * (1.f / 64.f);
    smu[tid] = m; srs[tid] = rsqrtf(q * (1.f / 64.f) - m * m + 1e-5f);
  }
  __syncthreads();
  {
    float m = smu[rtok], ri = srs[rtok];
    const int swz = (rtok & 7) << 4;
#pragma unroll
    for (int q8 = 0; q8 < 4; ++q8) {
      bf16x8 o;
#pragma unroll
      for (int j = 0; j < 8; ++j) {
        int c = c0own + q8 * 8 + j;
        o[j] = (short)f2bf_u((vx[q8 * 8 + j] - m) * ri * n1w[c] + n1b[c]);
      }
      *(bf16x8*)(sX + rtok * 128 + ((c0own * 2 + q8 * 16) ^ swz)) = o;
    }
  }
  __syncthreads();   // sX (LN1) + sW (cpw) ready

  // ---- GEMM machinery (M=128: 2 m-tiles/wave) ----
  const int fr = lane & 15, kq = lane >> 4;
  f32x4 acc[2][4], res[2][4];
  auto ZERO = [&](f32x4 a[2][4]) {
#pragma unroll
    for (int m = 0; m < 2; ++m)
#pragma unroll
      for (int nt = 0; nt < 4; ++nt) a[m][nt] = (f32x4){0.f, 0.f, 0.f, 0.f};
  };
  auto GEMM = [&](const char* A, f32x4 a[2][4]) {
#pragma unroll
    for (int kh = 0; kh < 2; ++kh) {
#pragma unroll
      for (int m = 0; m < 2; ++m) {
        int arow = wid * 32 + m * 16 + fr;
        bf16x8 af = *(const bf16x8*)(A + arow * 128 + ((kh * 64 + kq * 16) ^ ((arow & 7) << 4)));
#pragma unroll
        for (int nt = 0; nt < 4; ++nt) {
          int brow = nt * 16 + fr;
          bf16x8 bv = *(const bf16x8*)(sW + brow * 128 + ((kh * 64 + kq * 16) ^ ((brow & 7) << 4)));
          a[m][nt] = __builtin_amdgcn_mfma_f32_16x16x32_bf16(af, bv, a[m][nt], 0, 0, 0);
        }
      }
    }
  };
  auto EPI = [&](char* dst, f32x4 a[2][4], const float* bias) {
#pragma unroll
    for (int m = 0; m < 2; ++m) {
      int rb = wid * 32 + m * 16 + kq * 4;
#pragma unroll
      for (int nt = 0; nt < 4; ++nt) {
        int col = nt * 16 + fr;
        float bvv = bias[col];
#pragma unroll
        for (int reg = 0; reg < 4; ++reg) {
          int row = rb + reg;
          *(unsigned short*)(dst + row * 128 + ((2 * col) ^ ((row & 7) << 4))) =
              f2bf_u(a[m][nt][reg] + bvv);
        }
      }
    }
  };

  // --- GEMM1 convp: sX -> sQ0 ---
  ZERO(acc); GEMM(sX, acc); EPI(sQ, acc, cpb);
  __syncthreads();
  WSTORE(); WLOAD(tokw);          // pw1w -> sW
  __syncthreads();
  // --- GEMM2 pw1: sQ0 -> sQ1 ---
  ZERO(acc); GEMM(sQ, acc); EPI(sQ + 16384, acc, pw1b);
  __syncthreads();
  // --- dw1 depthwise over window sequence: sQ1 -> sQ0 ; stage tokw ---
  {
    const int c = tid & 63, tq = tid >> 6;
    float wv0 = dw1w[c * 3], wv1 = dw1w[c * 3 + 1], wv2 = dw1w[c * 3 + 2], bia = dw1b[c];
    const char* src = sQ + 16384;
#pragma unroll
    for (int wl = 0; wl < 2; ++wl) {
#pragma unroll
      for (int k = 0; k < 16; ++k) {
        int s = tq * 16 + k;
        int r0 = ((s >> 3) << 4) + wl * 8 + (s & 7);
        float v = bia + bf2f(*(const unsigned short*)(src + r0 * 128 + ((2 * c) ^ ((r0 & 7) << 4)))) * wv1;
        if (s > 0) {
          int rm = (((s - 1) >> 3) << 4) + wl * 8 + ((s - 1) & 7);
          v += bf2f(*(const unsigned short*)(src + rm * 128 + ((2 * c) ^ ((rm & 7) << 4)))) * wv0;
        }
        if (s < 63) {
          int rp = (((s + 1) >> 3) << 4) + wl * 8 + ((s + 1) & 7);
          v += bf2f(*(const unsigned short*)(src + rp * 128 + ((2 * c) ^ ((rp & 7) << 4)))) * wv2;
        }
        *(unsigned short*)(sQ + r0 * 128 + ((2 * c) ^ ((r0 & 7) << 4))) = f2bf_u(v);
      }
    }
  }
  WSTORE(); WLOAD(qkvw);          // tokw -> sW
  __syncthreads();
  // --- GEMM3 tok: sQ0 -> res ---
  ZERO(res); GEMM(sQ, res);
  __syncthreads();
  WSTORE(); WLOAD(qkvw + 4096);   // qkv g0 -> sW
  __syncthreads();
  ZERO(acc); GEMM(sX, acc); EPI(sQ, acc, qkvb);
  __syncthreads();
  WSTORE(); WLOAD(qkvw + 8192);   // qkv g1 -> sW
  __syncthreads();
  ZERO(acc); GEMM(sX, acc); EPI(sQ + 16384, acc, qkvb + 64);
  __syncthreads();
  WSTORE(); WLOAD(outw);          // qkv g2 -> sW
  __syncthreads();
  ZERO(acc); GEMM(sX, acc); EPI(sQ + 32768, acc, qkvb + 128);
  __syncthreads();
  WSTORE(); WLOAD(lpw);           // outw -> sW

  // --- per-token 4x4 head-axis attention: sQ tiles -> sX (ao) ---
  {
    const int r = tid & 127;
    const int hb = (tid >> 7) << 1;           // heads {hb, hb+1}
    const int s = ((r >> 4) << 3) + (r & 7);  // window-local token index
    const int swz = (r & 7) << 4;
    auto LD16 = [&](int gcol, float* o) {
      const char* base = sQ + ((gcol >> 6) * 16384) + r * 128;
      int c0 = (gcol & 63) * 2;
      bf16x8 u = *(const bf16x8*)(base + (c0 ^ swz));
      bf16x8 w2_ = *(const bf16x8*)(base + ((c0 + 16) ^ swz));
#pragma unroll
      for (int j = 0; j < 8; ++j) {
        o[j] = bf2f((unsigned short)u[j]); o[8 + j] = bf2f((unsigned short)w2_[j]);
      }
    };
    float q0[16], q1[16];
    LD16(48 * hb, q0);
    LD16(48 * hb + 48, q1);
    float sc0[4], sc1[4];
#pragma unroll
    for (int g = 0; g < 4; ++g) {
      float kk[16]; LD16(48 * g + 16, kk);
      float a0 = 0.f, a1 = 0.f;
#pragma unroll
      for (int d = 0; d < 16; ++d) { a0 += q0[d] * kk[d]; a1 += q1[d] * kk[d]; }
      sc0[g] = a0 * 0.25f + posb[s * 16 + hb * 4 + g];
      sc1[g] = a1 * 0.25f + posb[s * 16 + hb * 4 + 4 + g];
    }
    float m0 = fmaxf(fmaxf(sc0[0], sc0[1]), fmaxf(sc0[2], sc0[3]));
    float m1 = fmaxf(fmaxf(sc1[0], sc1[1]), fmaxf(sc1[2], sc1[3]));
    float e0[4], e1[4]; float t0 = 0.f, t1 = 0.f;
#pragma unroll
    for (int g = 0; g < 4; ++g) {
      e0[g] = expf(sc0[g] - m0); t0 += e0[g];
      e1[g] = expf(sc1[g] - m1); t1 += e1[g];
    }
    float i0 = 1.f / t0, i1 = 1.f / t1;
    float ao0[16], ao1[16];
#pragma unroll
    for (int d = 0; d < 16; ++d) { ao0[d] = 0.f; ao1[d] = 0.f; }
#pragma unroll
    for (int g = 0; g < 4; ++g) {
      float vv[16]; LD16(48 * g + 32, vv);
#pragma unroll
      for (int d = 0; d < 16; ++d) { ao0[d] += e0[g] * vv[d]; ao1[d] += e1[g] * vv[d]; }
    }
    bf16x8 o1, o2;
#pragma unroll
    for (int j = 0; j < 8; ++j) { o1[j] = (short)f2bf_u(ao0[j] * i0); o2[j] = (short)f2bf_u(ao0[8 + j] * i0); }
    *(bf16x8*)(sX + r * 128 + ((hb * 32) ^ swz)) = o1;
    *(bf16x8*)(sX + r * 128 + ((hb * 32 + 16) ^ swz)) = o2;
#pragma unroll
    for (int j = 0; j < 8; ++j) { o1[j] = (short)f2bf_u(ao1[j] * i1); o2[j] = (short)f2bf_u(ao1[8 + j] * i1); }
    *(bf16x8*)(sX + r * 128 + ((hb * 32 + 32) ^ swz)) = o1;
    *(bf16x8*)(sX + r * 128 + ((hb * 32 + 48) ^ swz)) = o2;
  }
  __syncthreads();
  // --- GEMM7 out-proj: sX(ao) -> res accumulate; fragments -> sQf (f32) ---
  GEMM(sX, res);
  {
#pragma unroll
    for (int nt = 0; nt < 4; ++nt) {
      int col = nt * 16 + fr;
      float ob = outb[col] + tokb[col];
#pragma unroll
      for (int m = 0; m < 2; ++m) {
        int rb = wid * 32 + m * 16 + kq * 4;
#pragma unroll
        for (int reg = 0; reg < 4; ++reg)
          sQf[(rb + reg) * 67 + col] = res[m][nt][reg] + ob;
      }
    }
  }
  __syncthreads();
  WSTORE();   // lpw -> sW
  // --- token-phase: residual add in registers + LN2 partials ---
  {
    float ss0 = 0.f, ss1 = 0.f;
#pragma unroll
    for (int k = 0; k < 32; ++k) {
      float v = sQf[rtok * 67 + c0own + k] + vx[k];
      vx[k] = v; ss0 += v; ss1 += v * v;
    }
    psA[cpar * 128 + rtok] = ss0;
    psB[cpar * 128 + rtok] = ss1;
  }
  __syncthreads();
  if (tid < 128) {
    float s = psA[tid] + psA[128 + tid];
    float q = psB[tid] + psB[128 + tid];
    float m = s * (1.f / 64.f);
    smu[tid] = m; srs[tid] = rsqrtf(q * (1.f / 64.f) - m * m + 1e-5f);
  }
  __syncthreads();
  // --- x1 store (bf16, vectorized) + LN2 normalize -> sX ---
  {
    float m = smu[rtok], ri = srs[rtok];
    const int swz = (rtok & 7) << 4;
    long t = ibase + (long)(h0 + (rtok >> 4)) * Ww + (w0 + (rtok & 15));
#pragma unroll
    for (int q8 = 0; q8 < 4; ++q8) {
      bf16x8 xo, no;
#pragma unroll
      for (int j = 0; j < 8; ++j) {
        int c = c0own + q8 * 8 + j;
        float v = vx[q8 * 8 + j];
        xo[j] = (short)f2bf_u(v);
        no[j] = (short)f2bf_u((v - m) * ri * n2w[c] + n2b[c]);
      }
      *(bf16x8*)((char*)x1g + t * 128 + (c0own + q8 * 8) * 2) = xo;
      *(bf16x8*)(sX + rtok * 128 + ((c0own * 2 + q8 * 16) ^ swz)) = no;
    }
  }
  __syncthreads();
  // --- GEMM8 LeFF-pw (no bias): sX -> sQf -> y (bf16, vectorized) ---
  ZERO(acc); GEMM(sX, acc);
  {
#pragma unroll
    for (int nt = 0; nt < 4; ++nt) {
      int col = nt * 16 + fr;
#pragma unroll
      for (int m = 0; m < 2; ++m) {
        int rb = wid * 32 + m * 16 + kq * 4;
#pragma unroll
        for (int reg = 0; reg < 4; ++reg)
          sQf[(rb + reg) * 67 + col] = acc[m][nt][reg];
      }
    }
  }
  __syncthreads();
  {
    long t = ibase + (long)(h0 + (rtok >> 4)) * Ww + (w0 + (rtok & 15));
#pragma unroll
    for (int q8 = 0; q8 < 4; ++q8) {
      bf16x8 o;
#pragma unroll
      for (int j = 0; j < 8; ++j)
        o[j] = (short)f2bf_u(sQf[rtok * 67 + c0own + q8 * 8 + j]);
      *(bf16x8*)((char*)yg + t * 128 + (c0own + q8 * 8) * 2) = o;
    }
  }
}

// ================= K_B: 3x3 depthwise + fc1+GELU+fc2 + residual + BCHW store =================

__global__ __launch_bounds__(256, 3) void kB(
    const unsigned short* __restrict__ yg, const unsigned short* __restrict__ x1g,
    float* __restrict__ out,
    const float* __restrict__ ldw, const float* __restrict__ ldb,
    const float* __restrict__ f1w, const float* __restrict__ f1b,
    const float* __restrict__ f2w, const float* __restrict__ f2b) {
  __shared__ char sZ0[8192];
  __shared__ char sZ1[8192];
  __shared__ char U[33792];      // halo (4x66x64 bf16) -> sW/sH0/sH1 -> sO
  __shared__ float wtab[640];    // [9][64] dw weights + [64] bias

  const int tid = threadIdx.x;
  const int lane = tid & 63, wid = tid >> 6;
  const int bid = blockIdx.x;
  const int b = bid / 1152;
  const int r2 = bid - b * 1152;
  const int hp = r2 / 6, wseg = r2 - (r2 / 6) * 6;
  const int h0 = hp * 2, w0 = wseg * 64;
  const long ibase = (long)b * HW;
  const int cbase = lane & 15;
  const int rbase = wid * 16 + (lane >> 4) * 4;

  // --- preload x1 residual fragments EARLY (consumed in epilogue) ---
  unsigned short x1r[2][4][4];
#pragma unroll
  for (int t = 0; t < 2; ++t) {
    const long p0t = ibase + (long)(h0 + t) * Ww + w0;
#pragma unroll
    for (int nt = 0; nt < 4; ++nt) {
      int col = nt * 16 + cbase;
#pragma unroll
      for (int reg = 0; reg < 4; ++reg)
        x1r[t][nt][reg] = x1g[(p0t + rbase + reg) * 64 + col];
    }
  }

#pragma unroll
  for (int it = 0; it < 3; ++it) {
    int idx = it * 256 + tid;
    if (idx < 576) wtab[idx] = ldw[(idx & 63) * 9 + (idx >> 6)];
    else if (idx < 640) wtab[idx] = ldb[idx - 576];
  }

  for (int it = 0; it < 9; ++it) {
    int idx = it * 256 + tid;
    if (idx >= 2112) break;
    int hr = idx / 528;
    int rq = idx - hr * 528;
    int px = rq >> 3, c8 = rq & 7;
    int h = h0 - 1 + hr, w = w0 - 1 + px;
    uint4 v = make_uint4(0, 0, 0, 0);
    if (h >= 0 && h < Hh && w >= 0 && w < Ww) {
      long t = ibase + (long)h * Ww + w;
      v = *(const uint4*)((const char*)yg + t * 128 + c8 * 16);
    }
    *(uint4*)(U + (hr * 66 + px) * 128 + c8 * 16) = v;
  }
  __syncthreads();

  {
    const int c8 = tid & 7, c0 = c8 * 8;
#pragma unroll
    for (int it = 0; it < 4; ++it) {
      int task = it * 256 + tid;
      int r = task >> 9;
      int px = (task >> 3) & 63;
      float a8[8];
#pragma unroll
      for (int j = 0; j < 8; ++j) a8[j] = wtab[576 + c0 + j];
#pragma unroll
      for (int dy = 0; dy < 3; ++dy)
#pragma unroll
        for (int dx = 0; dx < 3; ++dx) {
          bf16x8 v = *(const bf16x8*)(U + ((r + dy) * 66 + px + dx) * 128 + c8 * 16);
          const float* wk = wtab + (dy * 3 + dx) * 64 + c0;
#pragma unroll
          for (int j = 0; j < 8; ++j) a8[j] += bf2f((unsigned short)v[j]) * wk[j];
        }
      char* sZ = r ? sZ1 : sZ0;
      bf16x8 o;
#pragma unroll
      for (int j = 0; j < 8; ++j) o[j] = (short)f2bf_u(a8[j]);
      *(bf16x8*)(sZ + px * 128 + ((c8 * 16) ^ ((px & 7) << 4))) = o;
    }
  }
  __syncthreads();

  char* sW  = U;
  char* sH0 = U + 8192;
  char* sH1 = U + 16384;
  f32x4 res0[4], res1[4];
#pragma unroll
  for (int nt = 0; nt < 4; ++nt) { res0[nt] = (f32x4){0.f,0.f,0.f,0.f}; res1[nt] = (f32x4){0.f,0.f,0.f,0.f}; }

  for (int jc = 0; jc < 4; ++jc) {
    stage_wtile(sW, f1w + jc * 4096, 64, tid);
    __syncthreads();
#pragma unroll
    for (int t = 0; t < 2; ++t) {
      f32x4 acc[4];
#pragma unroll
      for (int nt = 0; nt < 4; ++nt) acc[nt] = (f32x4){0.f,0.f,0.f,0.f};
      mfma64(t ? sZ1 : sZ0, sW, wid, lane, acc);
      char* sH = t ? sH1 : sH0;
#pragma unroll
      for (int nt = 0; nt < 4; ++nt) {
        const int col = nt * 16 + cbase;
        const float bv = f1b[jc * 64 + col];
#pragma unroll
        for (int reg = 0; reg < 4; ++reg) {
          const int row = rbase + reg;
          *(unsigned short*)(sH + row * 128 + ((col * 2) ^ ((row & 7) << 4))) =
              f2bf_u(gelu_exact(acc[nt][reg] + bv));
        }
      }
    }
    __syncthreads();
    stage_wtile(sW, f2w + jc * 64, 256, tid);
    __syncthreads();
    mfma64(sH0, sW, wid, lane, res0);
    mfma64(sH1, sW, wid, lane, res1);
    __syncthreads();
  }

  float* sO = (float*)U;
#pragma unroll
  for (int t = 0; t < 2; ++t) {
    const f32x4* res = t ? res1 : res0;
#pragma unroll
    for (int nt = 0; nt < 4; ++nt) {
      const int col = nt * 16 + cbase;
      const float bv = f2b[col];
#pragma unroll
      for (int reg = 0; reg < 4; ++reg) {
        const int row = rbase + reg;
        sO[row * 65 + col] = res[nt][reg] + bv + bf2f(x1r[t][nt][reg]);
      }
    }
    __syncthreads();
#pragma unroll
    for (int it = 0; it < 16; ++it) {
      int c = it * 4 + (tid >> 6);
      int wo = tid & 63;
      out[(((long)(b * Cc + c)) * Hh + (h0 + t)) * Ww + w0 + wo] = sO[wo * 65 + c];
    }
    __syncthreads();
  }
}

// ---------------- launch ----------------

extern "C" void kernel_launch(void* const* d_in, const int* in_sizes, int n_in,
                              void* d_out, int out_size, void* d_ws, size_t ws_size,
                              hipStream_t stream) {
  const float* x    = (const float*)d_in[0];
  const float* n1w  = (const float*)d_in[1];
  const float* n1b  = (const float*)d_in[2];
  const float* qkvw = (const float*)d_in[3];
  const float* qkvb = (const float*)d_in[4];
  const float* posb = (const float*)d_in[5];
  const float* outw = (const float*)d_in[6];
  const float* outb = (const float*)d_in[7];
  const float* cpw  = (const float*)d_in[8];
  const float* cpb  = (const float*)d_in[9];
  const float* pw1w = (const float*)d_in[10];
  const float* pw1b = (const float*)d_in[11];
  const float* dw1w = (const float*)d_in[12];
  const float* dw1b = (const float*)d_in[13];
  const float* tokw = (const float*)d_in[14];
  const float* tokb = (const float*)d_in[15];
  const float* n2w  = (const float*)d_in[16];
  const float* n2b  = (const float*)d_in[17];
  const float* lpw  = (const float*)d_in[18];
  const float* ldw  = (const float*)d_in[19];
  const float* ldb  = (const float*)d_in[20];
  const float* f1w  = (const float*)d_in[21];
  const float* f1b  = (const float*)d_in[22];
  const float* f2w  = (const float*)d_in[23];
  const float* f2b  = (const float*)d_in[24];
  float* out = (float*)d_out;

  unsigned short* x1 = (unsigned short*)d_ws;        // bf16 [Tt][64]
  unsigned short* y  = x1 + (size_t)Tt * 64;         // bf16 [Tt][64]

  kA<<<dim3(2304), dim3(256), 0, stream>>>(x, x1, y, n1w, n1b, qkvw, qkvb, posb,
                                           outw, outb, cpw, cpb, pw1w, pw1b,
                                           dw1w, dw1b, tokw, tokb, n2w, n2b, lpw);
  kB<<<dim3(2304), dim3(256), 0, stream>>>(y, x1, out, ldw, ldb, f1w, f1b, f2w, f2b);
}